// Round 3
// baseline (2320.860 us; speedup 1.0000x reference)
//
#include <hip/hip_runtime.h>
#include <hip/hip_bf16.h>
#include <math.h>

__device__ __forceinline__ float softplus_f(float x) {
    return (x > 0.f) ? x + log1pf(expf(-x)) : log1pf(expf(x));
}

// ---------------- NIG head + uncertainty gate (pre-topk) -------------------
// one wave (64 lanes) per row; gpre[row] = clamp(exp(-4*s2),1e-4,1)*mask
__global__ void nig_gate_kernel(const float* __restrict__ Hbuf, const int* __restrict__ mask,
                                const float* __restrict__ nw, const float* __restrict__ nb,
                                float* __restrict__ gpre, float* __restrict__ sab) {
    int row = blockIdx.x;
    int lane = threadIdx.x;
    const float* hp = Hbuf + (size_t)row * 256;
    float a1 = 0.f, a2 = 0.f, a3 = 0.f;
    for (int d = lane; d < 256; d += 64) {
        float h = hp[d];
        a1 += h * nw[d * 4 + 1];
        a2 += h * nw[d * 4 + 2];
        a3 += h * nw[d * 4 + 3];
    }
#pragma unroll
    for (int o = 32; o; o >>= 1) {
        a1 += __shfl_xor(a1, o);
        a2 += __shfl_xor(a2, o);
        a3 += __shfl_xor(a3, o);
    }
    if (lane == 0) {
        float nu = softplus_f(a1 + nb[1]);
        float sa = softplus_f(a2 + nb[2]);          // alpha - 1
        float beta = softplus_f(a3 + nb[3]);
        float s2 = beta / (nu * sa + 1e-6f);
        float g = expf(-4.f * s2);
        g = fminf(fmaxf(g, 1e-4f), 1.f);
        gpre[row] = (mask[row] != 0) ? g : 0.f;
        atomicAdd(sab, (1.f + sa) + beta);          // alpha + beta
    }
}

// ---------------- per-batch top-k (stable argsort semantics) ---------------
__global__ void topk_kernel(const float* __restrict__ gpre, const int* __restrict__ mask,
                            float* __restrict__ gout, float* __restrict__ logg,
                            float* __restrict__ sg, float* __restrict__ sm, int N) {
    __shared__ float grow[1024];
    __shared__ float red[256];
    int b = blockIdx.x;
    int tid = threadIdx.x;
    int j = blockIdx.y * 256 + tid;
    for (int i = tid; i < N; i += 256) grow[i] = gpre[b * N + i];
    float cpart = 0.f;
    for (int i = tid; i < N; i += 256) cpart += (mask[b * N + i] != 0) ? 1.f : 0.f;
    red[tid] = cpart;
    __syncthreads();
    for (int s = 128; s; s >>= 1) { if (tid < s) red[tid] += red[tid + s]; __syncthreads(); }
    float count = red[0];
    __syncthreads();
    int k = (int)fmaxf(count * 0.5f, 1.0f);
    float gj = grow[j];
    int rank = 0;
    for (int i = 0; i < N; ++i) {
        float gi = grow[i];
        rank += (gi > gj || (gi == gj && i < j)) ? 1 : 0;
    }
    float gf = (rank < k) ? gj : 0.f;
    gout[b * N + j] = gf;
    logg[b * N + j] = logf(gf + 1e-8f);
    // sums for budget regularizer
    red[tid] = gf;
    __syncthreads();
    for (int s = 128; s; s >>= 1) { if (tid < s) red[tid] += red[tid + s]; __syncthreads(); }
    if (tid == 0) atomicAdd(sg, red[0]);
    __syncthreads();
    red[tid] = (mask[b * N + j] != 0) ? 1.f : 0.f;
    __syncthreads();
    for (int s = 128; s; s >>= 1) { if (tid < s) red[tid] += red[tid + s]; __syncthreads(); }
    if (tid == 0) atomicAdd(sm, red[0]);
}

// ---------------- C[M,256] = A[M,256] @ W[256,256] + bias (+resid) ---------
__global__ void gemm256_kernel(const float* __restrict__ A, const float* __restrict__ W,
                               const float* __restrict__ bias, const float* __restrict__ resid,
                               float* __restrict__ C) {
    __shared__ float As[64][17];
    __shared__ float Ws[16][68];
    int tid = threadIdx.x;
    int tx = tid & 15, ty = tid >> 4;
    size_t row0 = (size_t)blockIdx.x * 64;
    int col0 = blockIdx.y * 64;
    float acc[4][4] = {};
    for (int k0 = 0; k0 < 256; k0 += 16) {
        for (int i = tid; i < 1024; i += 256) {
            int r = i >> 4, c = i & 15;
            As[r][c] = A[(row0 + r) * 256 + k0 + c];
        }
        for (int i = tid; i < 1024; i += 256) {
            int r = i >> 6, c = i & 63;
            Ws[r][c] = W[(size_t)(k0 + r) * 256 + col0 + c];
        }
        __syncthreads();
#pragma unroll
        for (int kk = 0; kk < 16; ++kk) {
            float av[4], wv[4];
#pragma unroll
            for (int i = 0; i < 4; ++i) av[i] = As[ty * 4 + i][kk];
#pragma unroll
            for (int j = 0; j < 4; ++j) wv[j] = Ws[kk][tx * 4 + j];
#pragma unroll
            for (int i = 0; i < 4; ++i)
#pragma unroll
                for (int j = 0; j < 4; ++j) acc[i][j] += av[i] * wv[j];
        }
        __syncthreads();
    }
#pragma unroll
    for (int i = 0; i < 4; ++i) {
        size_t r = row0 + ty * 4 + i;
#pragma unroll
        for (int j = 0; j < 4; ++j) {
            int c = col0 + tx * 4 + j;
            float v = acc[i][j] + bias[c];
            if (resid) v += resid[r * 256 + c];
            C[r * 256 + c] = v;
        }
    }
}

// ---------------- attention: one wave per (b,h,q-row) ----------------------
template <int NK>
__global__ void attn_kernel(const float* __restrict__ qb, const float* __restrict__ kb,
                            const float* __restrict__ vb, const int* __restrict__ mask,
                            const float* __restrict__ logg, float* __restrict__ ctxb,
                            int Nq) {
    constexpr int NIT = NK / 64;
    __shared__ float wlds[4][NK];
    int wid = threadIdx.x >> 6, lane = threadIdx.x & 63;
    int row = blockIdx.x * 4 + wid;
    int b = row / (8 * Nq);
    int rem = row - b * 8 * Nq;
    int h = rem / Nq;
    int qi = rem - h * Nq;
    const float* qp = qb + ((size_t)(b * Nq + qi)) * 256 + h * 32;
    float qreg[32];
#pragma unroll
    for (int d = 0; d < 32; ++d) qreg[d] = qp[d];
    float s[NIT];
    float smax = -3.0e38f;
#pragma unroll
    for (int it = 0; it < NIT; ++it) {
        int kk = it * 64 + lane;
        const float* kp = kb + ((size_t)(b * NK + kk)) * 256 + h * 32;
        float dot = 0.f;
#pragma unroll
        for (int d = 0; d < 32; ++d) dot += qreg[d] * kp[d];
        dot *= 0.17677669529663687f;            // 1/sqrt(32)
        if (mask[b * NK + kk] == 0) dot = -1e30f;
        dot += logg[b * NK + kk];
        s[it] = dot;
        smax = fmaxf(smax, dot);
    }
#pragma unroll
    for (int o = 32; o; o >>= 1) smax = fmaxf(smax, __shfl_xor(smax, o));
    float sumw = 0.f;
#pragma unroll
    for (int it = 0; it < NIT; ++it) {
        float w = expf(s[it] - smax);
        sumw += w;
        wlds[wid][it * 64 + lane] = w;
    }
#pragma unroll
    for (int o = 32; o; o >>= 1) sumw += __shfl_xor(sumw, o);
    __syncthreads();
    int d = lane & 31, half = lane >> 5;
    float acc = 0.f;
    const float* vp = vb + ((size_t)b * NK) * 256 + h * 32 + d;
    for (int kk = half * (NK / 2); kk < (half + 1) * (NK / 2); ++kk) {
        acc += wlds[wid][kk] * vp[(size_t)kk * 256];
    }
    acc += __shfl_xor(acc, 32);
    if (lane < 32) ctxb[((size_t)(b * Nq + qi)) * 256 + h * 32 + lane] = acc / sumw;
}

// ---------------- row LayerNorm (256 cols), f32 out ------------------------
__global__ void ln_kernel(const float* __restrict__ X, const float* __restrict__ gam,
                          const float* __restrict__ bet, float* __restrict__ outp) {
    __shared__ float red[256];
    size_t row = blockIdx.x;
    int tid = threadIdx.x;
    float x = X[row * 256 + tid];
    red[tid] = x;
    __syncthreads();
    for (int s = 128; s; s >>= 1) { if (tid < s) red[tid] += red[tid + s]; __syncthreads(); }
    float mean = red[0] * (1.f / 256.f);
    __syncthreads();
    float dx = x - mean;
    red[tid] = dx * dx;
    __syncthreads();
    for (int s = 128; s; s >>= 1) { if (tid < s) red[tid] += red[tid + s]; __syncthreads(); }
    float var = red[0] * (1.f / 256.f);
    outp[row * 256 + tid] = dx * rsqrtf(var + 1e-5f) * gam[tid] + bet[tid];
}

// ---------------- scalar loss ---------------------------------------------
__global__ void loss_kernel(const float* __restrict__ red, float* __restrict__ out) {
    float t1 = red[2] / (red[3] + 1e-8f) - 0.3f;
    float t2 = red[4] / (red[5] + 1e-8f) - 0.3f;
    out[0] = 0.01f * (t1 * t1) + 0.01f * (t2 * t2)
           + 1e-3f * (red[0] / 4096.f) + 1e-3f * (red[1] / 8192.f);
}

extern "C" void kernel_launch(void* const* d_in, const int* in_sizes, int n_in,
                              void* d_out, int out_size, void* d_ws, size_t ws_size,
                              hipStream_t stream) {
    (void)in_sizes; (void)n_in; (void)out_size; (void)ws_size;
    const float* H_D   = (const float*)d_in[0];
    const int*   maskD = (const int*)d_in[1];
    const float* H_P   = (const float*)d_in[2];
    const int*   maskP = (const int*)d_in[3];
    const float* nig_w = (const float*)d_in[4];
    const float* nig_b = (const float*)d_in[5];
    const float* Wq = (const float*)d_in[6];
    const float* bq = (const float*)d_in[7];
    const float* Wk = (const float*)d_in[8];
    const float* bk = (const float*)d_in[9];
    const float* Wv = (const float*)d_in[10];
    const float* bv = (const float*)d_in[11];
    const float* Wo = (const float*)d_in[12];
    const float* bo = (const float*)d_in[13];
    const float* ln_g = (const float*)d_in[14];
    const float* ln_b = (const float*)d_in[15];
    float* out = (float*)d_out;
    float* ws = (float*)d_ws;

    // output offsets (f32 elements): Xd, Xp, g_D, g_P, loss
    float* outXd = out + 0;          // 1048576
    float* outXp = out + 1048576;    // 2097152
    float* outGD = out + 3145728;    // 4096
    float* outGP = out + 3149824;    // 8192
    float* outLo = out + 3158016;    // 1

    // workspace layout (floats), total ~25.3 MB
    float* red   = ws;               // 16 (6 used)
    float* gpreD = ws + 16;          // 4096
    float* gpreP = gpreD + 4096;     // 8192
    float* logD  = gpreP + 8192;     // 4096
    float* logP  = logD + 4096;      // 8192
    float* bufA  = logP + 8192;      // 1M: q1 / k2
    float* bufB  = bufA + 1048576;   // 2M: k1 / pre1 / ctx2
    float* bufC  = bufB + 2097152;   // 2M: v1 / q2 / pre2
    float* bufE  = bufC + 2097152;   // 1M: ctx1 / v2

    hipMemsetAsync(red, 0, 16 * sizeof(float), stream);

    // gates + regularizer sums
    nig_gate_kernel<<<4096, 64, 0, stream>>>(H_D, maskD, nig_w, nig_b, gpreD, red + 0);
    nig_gate_kernel<<<8192, 64, 0, stream>>>(H_P, maskP, nig_w, nig_b, gpreP, red + 1);
    topk_kernel<<<dim3(8, 2), 256, 0, stream>>>(gpreD, maskD, outGD, logD, red + 2, red + 3, 512);
    topk_kernel<<<dim3(8, 4), 256, 0, stream>>>(gpreP, maskP, outGP, logP, red + 4, red + 5, 1024);

    // MHCA1: queries H_D (4096 rows), kv H_P (8192 rows)
    gemm256_kernel<<<dim3(64, 4), 256, 0, stream>>>(H_D, Wq, bq, nullptr, bufA);   // q1
    gemm256_kernel<<<dim3(128, 4), 256, 0, stream>>>(H_P, Wk, bk, nullptr, bufB);  // k1
    gemm256_kernel<<<dim3(128, 4), 256, 0, stream>>>(H_P, Wv, bv, nullptr, bufC);  // v1
    attn_kernel<1024><<<8192, 256, 0, stream>>>(bufA, bufB, bufC, maskP, logP, bufE, 512);   // ctx1
    gemm256_kernel<<<dim3(64, 4), 256, 0, stream>>>(bufE, Wo, bo, H_D, bufB);      // pre1
    ln_kernel<<<4096, 256, 0, stream>>>(bufB, ln_g, ln_b, outXd);                  // Xd (f32, reused below)

    // MHCA2: queries H_P (8192 rows), kv = Xd (4096 rows)
    gemm256_kernel<<<dim3(128, 4), 256, 0, stream>>>(H_P, Wq, bq, nullptr, bufC);  // q2
    gemm256_kernel<<<dim3(64, 4), 256, 0, stream>>>(outXd, Wk, bk, nullptr, bufA); // k2
    gemm256_kernel<<<dim3(64, 4), 256, 0, stream>>>(outXd, Wv, bv, nullptr, bufE); // v2
    attn_kernel<512><<<16384, 256, 0, stream>>>(bufC, bufA, bufE, maskD, logD, bufB, 1024);  // ctx2
    gemm256_kernel<<<dim3(128, 4), 256, 0, stream>>>(bufB, Wo, bo, H_P, bufC);     // pre2
    ln_kernel<<<8192, 256, 0, stream>>>(bufC, ln_g, ln_b, outXp);

    loss_kernel<<<1, 1, 0, stream>>>(red, outLo);
}

// Round 4
// 636.891 us; speedup vs baseline: 3.6440x; 3.6440x over previous
//
#include <hip/hip_runtime.h>
#include <hip/hip_bf16.h>
#include <math.h>

typedef __attribute__((ext_vector_type(8))) short s8;
typedef __attribute__((ext_vector_type(4))) float f4;
typedef __attribute__((ext_vector_type(4))) unsigned short us4;

__device__ __forceinline__ unsigned short f2bf(float f) {
    unsigned int u = __float_as_uint(f);
    unsigned int r = u + 0x7FFFu + ((u >> 16) & 1u);   // RNE (no NaN inputs here)
    return (unsigned short)(r >> 16);
}

__device__ __forceinline__ float softplus_f(float x) {
    return (x > 0.f) ? x + log1pf(expf(-x)) : log1pf(expf(x));
}

// ---------------- NIG head + uncertainty gate (pre-topk) -------------------
__global__ void nig_gate_kernel(const float* __restrict__ Hbuf, const int* __restrict__ mask,
                                const float* __restrict__ nw, const float* __restrict__ nb,
                                float* __restrict__ gpre, float* __restrict__ sab) {
    int row = blockIdx.x;
    int lane = threadIdx.x;
    const float* hp = Hbuf + (size_t)row * 256;
    float a1 = 0.f, a2 = 0.f, a3 = 0.f;
    for (int d = lane; d < 256; d += 64) {
        float h = hp[d];
        a1 += h * nw[d * 4 + 1];
        a2 += h * nw[d * 4 + 2];
        a3 += h * nw[d * 4 + 3];
    }
#pragma unroll
    for (int o = 32; o; o >>= 1) {
        a1 += __shfl_xor(a1, o);
        a2 += __shfl_xor(a2, o);
        a3 += __shfl_xor(a3, o);
    }
    if (lane == 0) {
        float nu = softplus_f(a1 + nb[1]);
        float sa = softplus_f(a2 + nb[2]);          // alpha - 1
        float beta = softplus_f(a3 + nb[3]);
        float s2 = beta / (nu * sa + 1e-6f);
        float g = expf(-4.f * s2);
        g = fminf(fmaxf(g, 1e-4f), 1.f);
        gpre[row] = (mask[row] != 0) ? g : 0.f;
        atomicAdd(sab, (1.f + sa) + beta);          // alpha + beta
    }
}

// ---------------- per-batch top-k (stable argsort semantics) ---------------
__global__ void topk_kernel(const float* __restrict__ gpre, const int* __restrict__ mask,
                            float* __restrict__ gout, float* __restrict__ logg,
                            float* __restrict__ sg, float* __restrict__ sm, int N) {
    __shared__ float grow[1024];
    __shared__ float red[256];
    int b = blockIdx.x;
    int tid = threadIdx.x;
    int j = blockIdx.y * 256 + tid;
    for (int i = tid; i < N; i += 256) grow[i] = gpre[b * N + i];
    float cpart = 0.f;
    for (int i = tid; i < N; i += 256) cpart += (mask[b * N + i] != 0) ? 1.f : 0.f;
    red[tid] = cpart;
    __syncthreads();
    for (int s = 128; s; s >>= 1) { if (tid < s) red[tid] += red[tid + s]; __syncthreads(); }
    float count = red[0];
    __syncthreads();
    int k = (int)fmaxf(count * 0.5f, 1.0f);
    float gj = grow[j];
    int rank = 0;
    for (int i = 0; i < N; ++i) {
        float gi = grow[i];
        rank += (gi > gj || (gi == gj && i < j)) ? 1 : 0;
    }
    float gf = (rank < k) ? gj : 0.f;
    gout[b * N + j] = gf;
    logg[b * N + j] = logf(gf + 1e-8f);
    red[tid] = gf;
    __syncthreads();
    for (int s = 128; s; s >>= 1) { if (tid < s) red[tid] += red[tid + s]; __syncthreads(); }
    if (tid == 0) atomicAdd(sg, red[0]);
    __syncthreads();
    red[tid] = (mask[b * N + j] != 0) ? 1.f : 0.f;
    __syncthreads();
    for (int s = 128; s; s >>= 1) { if (tid < s) red[tid] += red[tid + s]; __syncthreads(); }
    if (tid == 0) atomicAdd(sm, red[0]);
}

// ---------------- C[M,256] = A[M,256] @ W[256,256] + bias (+resid) ---------
__global__ void gemm256_kernel(const float* __restrict__ A, const float* __restrict__ W,
                               const float* __restrict__ bias, const float* __restrict__ resid,
                               float* __restrict__ C) {
    __shared__ float As[64][17];
    __shared__ float Ws[16][68];
    int tid = threadIdx.x;
    int tx = tid & 15, ty = tid >> 4;
    size_t row0 = (size_t)blockIdx.x * 64;
    int col0 = blockIdx.y * 64;
    float acc[4][4] = {};
    for (int k0 = 0; k0 < 256; k0 += 16) {
        for (int i = tid; i < 1024; i += 256) {
            int r = i >> 4, c = i & 15;
            As[r][c] = A[(row0 + r) * 256 + k0 + c];
        }
        for (int i = tid; i < 1024; i += 256) {
            int r = i >> 6, c = i & 63;
            Ws[r][c] = W[(size_t)(k0 + r) * 256 + col0 + c];
        }
        __syncthreads();
#pragma unroll
        for (int kk = 0; kk < 16; ++kk) {
            float av[4], wv[4];
#pragma unroll
            for (int i = 0; i < 4; ++i) av[i] = As[ty * 4 + i][kk];
#pragma unroll
            for (int j = 0; j < 4; ++j) wv[j] = Ws[kk][tx * 4 + j];
#pragma unroll
            for (int i = 0; i < 4; ++i)
#pragma unroll
                for (int j = 0; j < 4; ++j) acc[i][j] += av[i] * wv[j];
        }
        __syncthreads();
    }
#pragma unroll
    for (int i = 0; i < 4; ++i) {
        size_t r = row0 + ty * 4 + i;
#pragma unroll
        for (int j = 0; j < 4; ++j) {
            int c = col0 + tx * 4 + j;
            float v = acc[i][j] + bias[c];
            if (resid) v += resid[r * 256 + c];
            C[r * 256 + c] = v;
        }
    }
}

// ---------------- fused flash attention (bf16 MFMA) ------------------------
// block = 4 waves; block handles (b, h, 64 q-rows); each wave owns 16 q-rows.
// S = Q.K^T via mfma_16x16x32; online softmax in registers; P bounced via LDS
// into A-frag layout; O += P.V via mfma. mask folded into logg.
template <int NK>
__global__ __launch_bounds__(256) void attn_mfma_kernel(
        const float* __restrict__ qb, const float* __restrict__ kb,
        const float* __restrict__ vb, const float* __restrict__ logg,
        float* __restrict__ ctxb, int Nq) {
    __shared__ unsigned short Kf[2048];       // K-frags: [ksub(4)][lane(64)][8]
    __shared__ unsigned short Vf[2048];       // V-frags: [kh*2+dh][lane(64)][8]
    __shared__ unsigned short Pf[4][1152];    // per-wave P: [16 q][72 pitch]
    __shared__ float lg[64];

    const int tid = threadIdx.x;
    const int wid = tid >> 6, lane = tid & 63;
    const int g = lane >> 4, lo = lane & 15;
    const int b = blockIdx.y >> 3, h = blockIdx.y & 7;
    const int q0 = blockIdx.x * 64 + wid * 16;
    const size_t bq = (size_t)b * Nq, bk = (size_t)b * NK;
    const float scale = 0.17677669529663687f;  // 1/sqrt(32)

    // Q A-frag: lane holds Q[q0+lo][h*32 + g*8 + j], j=0..7
    union { s8 v; unsigned short u[8]; } qf;
    {
        const float* qp = qb + (bq + q0 + lo) * 256 + h * 32 + g * 8;
        float4 x = *(const float4*)qp;
        float4 y = *(const float4*)(qp + 4);
        qf.u[0] = f2bf(x.x); qf.u[1] = f2bf(x.y); qf.u[2] = f2bf(x.z); qf.u[3] = f2bf(x.w);
        qf.u[4] = f2bf(y.x); qf.u[5] = f2bf(y.y); qf.u[6] = f2bf(y.z); qf.u[7] = f2bf(y.w);
    }

    f4 o0 = {0.f, 0.f, 0.f, 0.f}, o1 = {0.f, 0.f, 0.f, 0.f};
    float mrow[4] = {-3e38f, -3e38f, -3e38f, -3e38f};
    float lsum[4] = {0.f, 0.f, 0.f, 0.f};

    for (int kt = 0; kt < NK / 64; ++kt) {
        __syncthreads();   // prior tile fully consumed
        // ---- stage K & V tile (64 rows x 32 cols) into frag-order LDS ----
#pragma unroll
        for (int u = 0; u < 2; ++u) {
            int idx = tid + u * 256;           // 0..511
            int kloc = idx >> 3, quad = idx & 7;
            const float* kp = kb + (bk + kt * 64 + kloc) * 256 + h * 32 + quad * 4;
            float4 f = *(const float4*)kp;
            // K-frag: element (lane,j) = K[ksub*16 + (lane&15)][g*8+j]
            int ln16 = ((quad >> 1) << 4) | (kloc & 15);
            int addr = ((kloc >> 4) << 9) + ln16 * 8 + ((quad & 1) << 2);
            us4 pk = { f2bf(f.x), f2bf(f.y), f2bf(f.z), f2bf(f.w) };
            *(us4*)&Kf[addr] = pk;

            const float* vp = vb + (bk + kt * 64 + kloc) * 256 + h * 32 + quad * 4;
            float4 fv = *(const float4*)vp;
            // V-frag: element (kh,dh,lane,j) = V[kh*32 + g*8 + j][dh*16 + (lane&15)]
            int kh = kloc >> 5, gg = (kloc >> 3) & 3, j = kloc & 7;
            int dh = quad >> 2, dl0 = (quad & 3) * 4;
            int vb0 = ((kh * 2 + dh) << 9) + gg * 128 + j;
            Vf[vb0 + (dl0 + 0) * 8] = f2bf(fv.x);
            Vf[vb0 + (dl0 + 1) * 8] = f2bf(fv.y);
            Vf[vb0 + (dl0 + 2) * 8] = f2bf(fv.z);
            Vf[vb0 + (dl0 + 3) * 8] = f2bf(fv.w);
        }
        if (tid < 64) lg[tid] = logg[bk + kt * 64 + tid];
        __syncthreads();

        // ---- scores: 4 MFMAs -> S[q=(g*4+r)][k=ks*16+lo] ----
        f4 sc[4];
#pragma unroll
        for (int ks = 0; ks < 4; ++ks) {
            s8 kfr = *(const s8*)&Kf[(ks << 9) + lane * 8];
            f4 z = {0.f, 0.f, 0.f, 0.f};
            f4 s4 = __builtin_amdgcn_mfma_f32_16x16x32_bf16(qf.v, kfr, z, 0, 0, 0);
            float lga = lg[ks * 16 + lo];
#pragma unroll
            for (int r = 0; r < 4; ++r) sc[ks][r] = s4[r] * scale + lga;
        }
        // ---- online softmax ----
        float vm[4];
#pragma unroll
        for (int r = 0; r < 4; ++r)
            vm[r] = fmaxf(fmaxf(sc[0][r], sc[1][r]), fmaxf(sc[2][r], sc[3][r]));
#pragma unroll
        for (int off = 1; off < 16; off <<= 1)
#pragma unroll
            for (int r = 0; r < 4; ++r) vm[r] = fmaxf(vm[r], __shfl_xor(vm[r], off));
        float al[4], ps[4];
#pragma unroll
        for (int r = 0; r < 4; ++r) {
            float mn = fmaxf(mrow[r], vm[r]);
            al[r] = __expf(mrow[r] - mn);
            mrow[r] = mn;
            ps[r] = 0.f;
        }
#pragma unroll
        for (int ks = 0; ks < 4; ++ks)
#pragma unroll
            for (int r = 0; r < 4; ++r) {
                float p = __expf(sc[ks][r] - mrow[r]);
                ps[r] += p;
                Pf[wid][(g * 4 + r) * 72 + ks * 16 + lo] = f2bf(p);
            }
#pragma unroll
        for (int off = 1; off < 16; off <<= 1)
#pragma unroll
            for (int r = 0; r < 4; ++r) ps[r] += __shfl_xor(ps[r], off);
#pragma unroll
        for (int r = 0; r < 4; ++r) {
            lsum[r] = lsum[r] * al[r] + ps[r];
            o0[r] *= al[r];
            o1[r] *= al[r];
        }
        // ---- PV: O[q][d] += P[q][k] * V[k][d] ----
#pragma unroll
        for (int kh = 0; kh < 2; ++kh) {
            s8 pfr = *(const s8*)&Pf[wid][lo * 72 + kh * 32 + g * 8];
            s8 vf0 = *(const s8*)&Vf[((kh * 2 + 0) << 9) + lane * 8];
            o0 = __builtin_amdgcn_mfma_f32_16x16x32_bf16(pfr, vf0, o0, 0, 0, 0);
            s8 vf1 = *(const s8*)&Vf[((kh * 2 + 1) << 9) + lane * 8];
            o1 = __builtin_amdgcn_mfma_f32_16x16x32_bf16(pfr, vf1, o1, 0, 0, 0);
        }
    }
    // ---- epilogue ----
#pragma unroll
    for (int r = 0; r < 4; ++r) {
        float inv = 1.f / lsum[r];
        float* cp = ctxb + (bq + q0 + g * 4 + r) * 256 + h * 32;
        cp[lo] = o0[r] * inv;
        cp[16 + lo] = o1[r] * inv;
    }
}

// ---------------- row LayerNorm (256 cols), f32 out ------------------------
__global__ void ln_kernel(const float* __restrict__ X, const float* __restrict__ gam,
                          const float* __restrict__ bet, float* __restrict__ outp) {
    __shared__ float red[256];
    size_t row = blockIdx.x;
    int tid = threadIdx.x;
    float x = X[row * 256 + tid];
    red[tid] = x;
    __syncthreads();
    for (int s = 128; s; s >>= 1) { if (tid < s) red[tid] += red[tid + s]; __syncthreads(); }
    float mean = red[0] * (1.f / 256.f);
    __syncthreads();
    float dx = x - mean;
    red[tid] = dx * dx;
    __syncthreads();
    for (int s = 128; s; s >>= 1) { if (tid < s) red[tid] += red[tid + s]; __syncthreads(); }
    float var = red[0] * (1.f / 256.f);
    outp[row * 256 + tid] = dx * rsqrtf(var + 1e-5f) * gam[tid] + bet[tid];
}

// ---------------- scalar loss ---------------------------------------------
__global__ void loss_kernel(const float* __restrict__ red, float* __restrict__ out) {
    float t1 = red[2] / (red[3] + 1e-8f) - 0.3f;
    float t2 = red[4] / (red[5] + 1e-8f) - 0.3f;
    out[0] = 0.01f * (t1 * t1) + 0.01f * (t2 * t2)
           + 1e-3f * (red[0] / 4096.f) + 1e-3f * (red[1] / 8192.f);
}

extern "C" void kernel_launch(void* const* d_in, const int* in_sizes, int n_in,
                              void* d_out, int out_size, void* d_ws, size_t ws_size,
                              hipStream_t stream) {
    (void)in_sizes; (void)n_in; (void)out_size; (void)ws_size;
    const float* H_D   = (const float*)d_in[0];
    const int*   maskD = (const int*)d_in[1];
    const float* H_P   = (const float*)d_in[2];
    const int*   maskP = (const int*)d_in[3];
    const float* nig_w = (const float*)d_in[4];
    const float* nig_b = (const float*)d_in[5];
    const float* Wq = (const float*)d_in[6];
    const float* bq = (const float*)d_in[7];
    const float* Wk = (const float*)d_in[8];
    const float* bk = (const float*)d_in[9];
    const float* Wv = (const float*)d_in[10];
    const float* bv = (const float*)d_in[11];
    const float* Wo = (const float*)d_in[12];
    const float* bo = (const float*)d_in[13];
    const float* ln_g = (const float*)d_in[14];
    const float* ln_b = (const float*)d_in[15];
    float* out = (float*)d_out;
    float* ws = (float*)d_ws;

    // output offsets (f32): Xd, Xp, g_D, g_P, loss
    float* outXd = out + 0;
    float* outXp = out + 1048576;
    float* outGD = out + 3145728;
    float* outGP = out + 3149824;
    float* outLo = out + 3158016;

    // workspace layout (floats)
    float* red   = ws;               // 16 (6 used)
    float* gpreD = ws + 16;          // 4096
    float* gpreP = gpreD + 4096;     // 8192
    float* logD  = gpreP + 8192;     // 4096
    float* logP  = logD + 4096;      // 8192
    float* bufA  = logP + 8192;      // 1M: q1 / k2
    float* bufB  = bufA + 1048576;   // 2M: k1 / pre1 / ctx2
    float* bufC  = bufB + 2097152;   // 2M: v1 / q2 / pre2
    float* bufE  = bufC + 2097152;   // 1M: ctx1 / v2

    hipMemsetAsync(red, 0, 16 * sizeof(float), stream);

    // gates + regularizer sums
    nig_gate_kernel<<<4096, 64, 0, stream>>>(H_D, maskD, nig_w, nig_b, gpreD, red + 0);
    nig_gate_kernel<<<8192, 64, 0, stream>>>(H_P, maskP, nig_w, nig_b, gpreP, red + 1);
    topk_kernel<<<dim3(8, 2), 256, 0, stream>>>(gpreD, maskD, outGD, logD, red + 2, red + 3, 512);
    topk_kernel<<<dim3(8, 4), 256, 0, stream>>>(gpreP, maskP, outGP, logP, red + 4, red + 5, 1024);

    // MHCA1: queries H_D (4096 rows), kv H_P (8192 rows)
    gemm256_kernel<<<dim3(64, 4), 256, 0, stream>>>(H_D, Wq, bq, nullptr, bufA);   // q1
    gemm256_kernel<<<dim3(128, 4), 256, 0, stream>>>(H_P, Wk, bk, nullptr, bufB);  // k1
    gemm256_kernel<<<dim3(128, 4), 256, 0, stream>>>(H_P, Wv, bv, nullptr, bufC);  // v1
    attn_mfma_kernel<1024><<<dim3(8, 64), 256, 0, stream>>>(bufA, bufB, bufC, logP, bufE, 512);  // ctx1
    gemm256_kernel<<<dim3(64, 4), 256, 0, stream>>>(bufE, Wo, bo, H_D, bufB);      // pre1
    ln_kernel<<<4096, 256, 0, stream>>>(bufB, ln_g, ln_b, outXd);                  // Xd

    // MHCA2: queries H_P (8192 rows), kv = Xd (4096 rows)
    gemm256_kernel<<<dim3(128, 4), 256, 0, stream>>>(H_P, Wq, bq, nullptr, bufC);  // q2
    gemm256_kernel<<<dim3(64, 4), 256, 0, stream>>>(outXd, Wk, bk, nullptr, bufA); // k2
    gemm256_kernel<<<dim3(64, 4), 256, 0, stream>>>(outXd, Wv, bv, nullptr, bufE); // v2
    attn_mfma_kernel<512><<<dim3(16, 64), 256, 0, stream>>>(bufC, bufA, bufE, logD, bufB, 1024); // ctx2
    gemm256_kernel<<<dim3(128, 4), 256, 0, stream>>>(bufB, Wo, bo, H_P, bufC);     // pre2
    ln_kernel<<<8192, 256, 0, stream>>>(bufC, ln_g, ln_b, outXp);

    loss_kernel<<<1, 1, 0, stream>>>(red, outLo);
}

// Round 6
// 295.939 us; speedup vs baseline: 7.8424x; 2.1521x over previous
//
#include <hip/hip_runtime.h>
#include <hip/hip_bf16.h>
#include <math.h>

typedef __attribute__((ext_vector_type(8))) short s8;
typedef __attribute__((ext_vector_type(8))) unsigned short us8;
typedef __attribute__((ext_vector_type(4))) float f4;

__device__ __forceinline__ unsigned short f2bf(float f) {
    unsigned int u = __float_as_uint(f);
    unsigned int r = u + 0x7FFFu + ((u >> 16) & 1u);   // RNE (no NaNs here)
    return (unsigned short)(r >> 16);
}

__device__ __forceinline__ float softplus_f(float x) {
    return (x > 0.f) ? x + log1pf(expf(-x)) : log1pf(expf(x));
}

// ---------------- W -> W^T bf16 (Wt[n][k] = W[k][n]) -----------------------
__global__ void prep_wt_kernel(const float* __restrict__ W0, const float* __restrict__ W1,
                               const float* __restrict__ W2, const float* __restrict__ W3,
                               unsigned short* __restrict__ Wt) {
    __shared__ float t[32][33];
    const float* W = blockIdx.z == 0 ? W0 : blockIdx.z == 1 ? W1 : blockIdx.z == 2 ? W2 : W3;
    unsigned short* O = Wt + blockIdx.z * 65536;
    int k0 = blockIdx.x * 32, n0 = blockIdx.y * 32;
    int r = threadIdx.x >> 5, c = threadIdx.x & 31;
#pragma unroll
    for (int i = 0; i < 4; ++i) t[r + i * 8][c] = W[(k0 + r + i * 8) * 256 + n0 + c];
    __syncthreads();
#pragma unroll
    for (int i = 0; i < 4; ++i) O[(n0 + r + i * 8) * 256 + k0 + c] = f2bf(t[c][r + i * 8]);
}

// ---------------- NIG head + uncertainty gate (pre-topk) -------------------
// one wave per row; (alpha+beta) scattered into 256 slots (no hot atomic)
__global__ void nig_gate_kernel(const float* __restrict__ Hbuf, const int* __restrict__ mask,
                                const float* __restrict__ nw, const float* __restrict__ nb,
                                float* __restrict__ gpre, float* __restrict__ slots) {
    int row = blockIdx.x;
    int lane = threadIdx.x;
    const float* hp = Hbuf + (size_t)row * 256;
    float a1 = 0.f, a2 = 0.f, a3 = 0.f;
    for (int d = lane; d < 256; d += 64) {
        float h = hp[d];
        a1 += h * nw[d * 4 + 1];
        a2 += h * nw[d * 4 + 2];
        a3 += h * nw[d * 4 + 3];
    }
#pragma unroll
    for (int o = 32; o; o >>= 1) {
        a1 += __shfl_xor(a1, o);
        a2 += __shfl_xor(a2, o);
        a3 += __shfl_xor(a3, o);
    }
    if (lane == 0) {
        float nu = softplus_f(a1 + nb[1]);
        float sa = softplus_f(a2 + nb[2]);          // alpha - 1
        float beta = softplus_f(a3 + nb[3]);
        float s2 = beta / (nu * sa + 1e-6f);
        float g = expf(-4.f * s2);
        g = fminf(fmaxf(g, 1e-4f), 1.f);
        gpre[row] = (mask[row] != 0) ? g : 0.f;
        atomicAdd(&slots[blockIdx.x & 255], (1.f + sa) + beta);   // alpha + beta
    }
}

// ---------------- per-batch top-k (stable argsort semantics) ---------------
__global__ void topk_kernel(const float* __restrict__ gpre, const int* __restrict__ mask,
                            float* __restrict__ gout, float* __restrict__ logg,
                            float* __restrict__ sg, float* __restrict__ sm, int N) {
    __shared__ float grow[1024];
    __shared__ float red[256];
    int b = blockIdx.x;
    int tid = threadIdx.x;
    int j = blockIdx.y * 256 + tid;
    for (int i = tid; i < N; i += 256) grow[i] = gpre[b * N + i];
    float cpart = 0.f;
    for (int i = tid; i < N; i += 256) cpart += (mask[b * N + i] != 0) ? 1.f : 0.f;
    red[tid] = cpart;
    __syncthreads();
    for (int s = 128; s; s >>= 1) { if (tid < s) red[tid] += red[tid + s]; __syncthreads(); }
    float count = red[0];
    __syncthreads();
    int k = (int)fmaxf(count * 0.5f, 1.0f);
    float gj = grow[j];
    int rank = 0;
    for (int i = 0; i < N; ++i) {
        float gi = grow[i];
        rank += (gi > gj || (gi == gj && i < j)) ? 1 : 0;
    }
    float gf = (rank < k) ? gj : 0.f;
    gout[b * N + j] = gf;
    logg[b * N + j] = logf(gf + 1e-8f);
    red[tid] = gf;
    __syncthreads();
    for (int s = 128; s; s >>= 1) { if (tid < s) red[tid] += red[tid + s]; __syncthreads(); }
    if (tid == 0) atomicAdd(sg, red[0]);
    __syncthreads();
    red[tid] = (mask[b * N + j] != 0) ? 1.f : 0.f;
    __syncthreads();
    for (int s = 128; s; s >>= 1) { if (tid < s) red[tid] += red[tid + s]; __syncthreads(); }
    if (tid == 0) atomicAdd(sm, red[0]);
}

// ---------------- QKV projection: Cb[M,256](bf16) = A(f32) @ W + bias ------
// block 256 = 4 waves; wave: 16 rows x 128 cols; grid (M/64, 2). No LDS:
// A frags converted in-reg, B frags are contiguous rows of Wt (bf16, L1-hot).
__global__ __launch_bounds__(256) void gemm_qkv_kernel(
        const float* __restrict__ A, const unsigned short* __restrict__ Wt,
        const float* __restrict__ bias, unsigned short* __restrict__ Cb) {
    const int tid = threadIdx.x, wid = tid >> 6, lane = tid & 63;
    const int g = lane >> 4, lo = lane & 15;
    const size_t row0 = (size_t)blockIdx.x * 64 + wid * 16;
    const int n0 = blockIdx.y * 128;
    f4 acc[8];
#pragma unroll
    for (int f = 0; f < 8; ++f) acc[f] = (f4){0.f, 0.f, 0.f, 0.f};
    for (int k0 = 0; k0 < 256; k0 += 32) {
        s8 av;
        const float* ap = A + (row0 + lo) * 256 + k0 + g * 8;
        float4 x = *(const float4*)ap, y = *(const float4*)(ap + 4);
        av[0] = (short)f2bf(x.x); av[1] = (short)f2bf(x.y);
        av[2] = (short)f2bf(x.z); av[3] = (short)f2bf(x.w);
        av[4] = (short)f2bf(y.x); av[5] = (short)f2bf(y.y);
        av[6] = (short)f2bf(y.z); av[7] = (short)f2bf(y.w);
#pragma unroll
        for (int f = 0; f < 8; ++f) {
            s8 bfr = *(const s8*)&Wt[(size_t)(n0 + f * 16 + lo) * 256 + k0 + g * 8];
            acc[f] = __builtin_amdgcn_mfma_f32_16x16x32_bf16(av, bfr, acc[f], 0, 0, 0);
        }
    }
#pragma unroll
    for (int f = 0; f < 8; ++f) {
        int col = n0 + f * 16 + lo;
        float bv = bias[col];
#pragma unroll
        for (int r = 0; r < 4; ++r)
            Cb[(row0 + g * 4 + r) * 256 + col] = f2bf(acc[f][r] + bv);
    }
}

// ---------------- Wo GEMM + bias + residual + LayerNorm (fused) ------------
// block 256 = 4 waves; wave: 16 rows x all 256 cols; grid (M/64).
__global__ __launch_bounds__(256) void gemm_o_ln_kernel(
        const unsigned short* __restrict__ A, const unsigned short* __restrict__ Wt,
        const float* __restrict__ bias, const float* __restrict__ resid,
        const float* __restrict__ gam, const float* __restrict__ bet,
        float* __restrict__ Out) {
    const int tid = threadIdx.x, wid = tid >> 6, lane = tid & 63;
    const int g = lane >> 4, lo = lane & 15;
    const size_t row0 = (size_t)blockIdx.x * 64 + wid * 16;
    f4 acc[16];
#pragma unroll
    for (int f = 0; f < 16; ++f) acc[f] = (f4){0.f, 0.f, 0.f, 0.f};
    for (int k0 = 0; k0 < 256; k0 += 32) {
        s8 af = *(const s8*)&A[(row0 + lo) * 256 + k0 + g * 8];
#pragma unroll
        for (int f = 0; f < 16; ++f) {
            s8 bfr = *(const s8*)&Wt[(size_t)(f * 16 + lo) * 256 + k0 + g * 8];
            acc[f] = __builtin_amdgcn_mfma_f32_16x16x32_bf16(af, bfr, acc[f], 0, 0, 0);
        }
    }
#pragma unroll
    for (int r = 0; r < 4; ++r) {
        size_t row = row0 + g * 4 + r;
        float s = 0.f;
#pragma unroll
        for (int f = 0; f < 16; ++f) {
            int col = f * 16 + lo;
            float v = acc[f][r] + bias[col] + resid[row * 256 + col];
            acc[f][r] = v;
            s += v;
        }
#pragma unroll
        for (int o = 1; o < 16; o <<= 1) s += __shfl_xor(s, o);
        float mean = s * (1.f / 256.f);
        float vs = 0.f;
#pragma unroll
        for (int f = 0; f < 16; ++f) {
            float dx = acc[f][r] - mean;
            vs += dx * dx;
        }
#pragma unroll
        for (int o = 1; o < 16; o <<= 1) vs += __shfl_xor(vs, o);
        float inv = rsqrtf(vs * (1.f / 256.f) + 1e-5f);
#pragma unroll
        for (int f = 0; f < 16; ++f) {
            int col = f * 16 + lo;
            Out[row * 256 + col] = (acc[f][r] - mean) * inv * gam[col] + bet[col];
        }
    }
}

// ---------------- fused flash attention (bf16 in, bf16 out) ----------------
template <int NK>
__global__ __launch_bounds__(256) void attn_mfma_kernel(
        const unsigned short* __restrict__ qb, const unsigned short* __restrict__ kb,
        const unsigned short* __restrict__ vb, const float* __restrict__ logg,
        unsigned short* __restrict__ ctxb, int Nq) {
    __shared__ unsigned short Kf[2048];       // K-frags: [ksub(4)][lane(64)][8]
    __shared__ unsigned short Vf[2048];       // V-frags: [kh*2+dh][lane(64)][8]
    __shared__ unsigned short Pf[4][1152];    // per-wave P: [16 q][72 pitch]
    __shared__ float lg[64];

    const int tid = threadIdx.x;
    const int wid = tid >> 6, lane = tid & 63;
    const int g = lane >> 4, lo = lane & 15;
    const int b = blockIdx.y >> 3, h = blockIdx.y & 7;
    const int q0 = blockIdx.x * 64 + wid * 16;
    const size_t bq = (size_t)b * Nq, bk = (size_t)b * NK;
    const float scale = 0.17677669529663687f;  // 1/sqrt(32)

    s8 qf = *(const s8*)&qb[(bq + q0 + lo) * 256 + h * 32 + g * 8];

    f4 o0 = {0.f, 0.f, 0.f, 0.f}, o1 = {0.f, 0.f, 0.f, 0.f};
    float mrow[4] = {-3e38f, -3e38f, -3e38f, -3e38f};
    float lsum[4] = {0.f, 0.f, 0.f, 0.f};

    for (int kt = 0; kt < NK / 64; ++kt) {
        __syncthreads();   // prior tile fully consumed
        {
            int kloc = tid >> 2, quad = tid & 3;
            us8 kv8 = *(const us8*)&kb[(bk + kt * 64 + kloc) * 256 + h * 32 + quad * 8];
            *(us8*)&Kf[((kloc >> 4) << 9) + (quad * 16 + (kloc & 15)) * 8] = kv8;
            us8 vv8 = *(const us8*)&vb[(bk + kt * 64 + kloc) * 256 + h * 32 + quad * 8];
            int kh = kloc >> 5, gg = (kloc >> 3) & 3, j = kloc & 7;
            int dh = quad >> 1, l0 = (quad & 1) * 8;
            int vb0 = ((kh * 2 + dh) << 9) + gg * 128 + j;
#pragma unroll
            for (int jj = 0; jj < 8; ++jj) Vf[vb0 + (l0 + jj) * 8] = vv8[jj];
        }
        if (tid < 64) lg[tid] = logg[bk + kt * 64 + tid];
        __syncthreads();

        // ---- scores ----
        f4 sc[4];
#pragma unroll
        for (int ks = 0; ks < 4; ++ks) {
            s8 kfr = *(const s8*)&Kf[(ks << 9) + lane * 8];
            f4 z = {0.f, 0.f, 0.f, 0.f};
            f4 s4 = __builtin_amdgcn_mfma_f32_16x16x32_bf16(qf, kfr, z, 0, 0, 0);
            float lga = lg[ks * 16 + lo];
#pragma unroll
            for (int r = 0; r < 4; ++r) sc[ks][r] = s4[r] * scale + lga;
        }
        // ---- online softmax ----
        float vm[4];
#pragma unroll
        for (int r = 0; r < 4; ++r)
            vm[r] = fmaxf(fmaxf(sc[0][r], sc[1][r]), fmaxf(sc[2][r], sc[3][r]));
#pragma unroll
        for (int off = 1; off < 16; off <<= 1)
#pragma unroll
            for (int r = 0; r < 4; ++r) vm[r] = fmaxf(vm[r], __shfl_xor(vm[r], off));
        float al[4], ps[4];
#pragma unroll
        for (int r = 0; r < 4; ++r) {
            float mn = fmaxf(mrow[r], vm[r]);
            al[r] = __expf(mrow[r] - mn);
            mrow[r] = mn;
            ps[r] = 0.f;
        }
#pragma unroll
        for (int ks = 0; ks < 4; ++ks)
#pragma unroll
            for (int r = 0; r < 4; ++r) {
                float p = __expf(sc[ks][r] - mrow[r]);
                ps[r] += p;
                Pf[wid][(g * 4 + r) * 72 + ks * 16 + lo] = f2bf(p);
            }
#pragma unroll
        for (int off = 1; off < 16; off <<= 1)
#pragma unroll
            for (int r = 0; r < 4; ++r) ps[r] += __shfl_xor(ps[r], off);
#pragma unroll
        for (int r = 0; r < 4; ++r) {
            lsum[r] = lsum[r] * al[r] + ps[r];
            o0[r] *= al[r];
            o1[r] *= al[r];
        }
        // ---- PV ----
#pragma unroll
        for (int kh = 0; kh < 2; ++kh) {
            s8 pfr = *(const s8*)&Pf[wid][lo * 72 + kh * 32 + g * 8];
            s8 vf0 = *(const s8*)&Vf[((kh * 2 + 0) << 9) + lane * 8];
            o0 = __builtin_amdgcn_mfma_f32_16x16x32_bf16(pfr, vf0, o0, 0, 0, 0);
            s8 vf1 = *(const s8*)&Vf[((kh * 2 + 1) << 9) + lane * 8];
            o1 = __builtin_amdgcn_mfma_f32_16x16x32_bf16(pfr, vf1, o1, 0, 0, 0);
        }
    }
    // ---- epilogue (bf16 ctx) ----
#pragma unroll
    for (int r = 0; r < 4; ++r) {
        float inv = 1.f / lsum[r];
        unsigned short* cp = ctxb + (bq + q0 + g * 4 + r) * 256 + h * 32;
        cp[lo] = f2bf(o0[r] * inv);
        cp[16 + lo] = f2bf(o1[r] * inv);
    }
}

// ---------------- final loss (reduce slot arrays) --------------------------
__global__ void loss_kernel(const float* __restrict__ redD, const float* __restrict__ redP,
                            const float* __restrict__ red4, float* __restrict__ out) {
    __shared__ float l1[256], l2[256];
    int t = threadIdx.x;
    l1[t] = redD[t];
    l2[t] = redP[t];
    __syncthreads();
    for (int s = 128; s; s >>= 1) {
        if (t < s) { l1[t] += l1[t + s]; l2[t] += l2[t + s]; }
        __syncthreads();
    }
    if (t == 0) {
        float t1 = red4[0] / (red4[1] + 1e-8f) - 0.3f;
        float t2 = red4[2] / (red4[3] + 1e-8f) - 0.3f;
        out[0] = 0.01f * (t1 * t1) + 0.01f * (t2 * t2)
               + 1e-3f * (l1[0] / 4096.f) + 1e-3f * (l2[0] / 8192.f);
    }
}

extern "C" void kernel_launch(void* const* d_in, const int* in_sizes, int n_in,
                              void* d_out, int out_size, void* d_ws, size_t ws_size,
                              hipStream_t stream) {
    (void)in_sizes; (void)n_in; (void)out_size; (void)ws_size;
    const float* H_D   = (const float*)d_in[0];
    const int*   maskD = (const int*)d_in[1];
    const float* H_P   = (const float*)d_in[2];
    const int*   maskP = (const int*)d_in[3];
    const float* nig_w = (const float*)d_in[4];
    const float* nig_b = (const float*)d_in[5];
    const float* Wq = (const float*)d_in[6];
    const float* bq = (const float*)d_in[7];
    const float* Wk = (const float*)d_in[8];
    const float* bk = (const float*)d_in[9];
    const float* Wv = (const float*)d_in[10];
    const float* bv = (const float*)d_in[11];
    const float* Wo = (const float*)d_in[12];
    const float* bo = (const float*)d_in[13];
    const float* ln_g = (const float*)d_in[14];
    const float* ln_b = (const float*)d_in[15];
    float* out = (float*)d_out;
    float* ws = (float*)d_ws;

    // output offsets (f32): Xd, Xp, g_D, g_P, loss
    float* outXd = out + 0;
    float* outXp = out + 1048576;
    float* outGD = out + 3145728;
    float* outGP = out + 3149824;
    float* outLo = out + 3158016;

    // f32 workspace
    float* redD  = ws;               // 256 slots
    float* redP  = ws + 256;         // 256 slots
    float* red4  = ws + 512;         // 16 (4 used: sgD,smD,sgP,smP)
    float* gpreD = ws + 528;         // 4096
    float* gpreP = ws + 4624;        // 8192
    float* logD  = ws + 12816;       // 4096
    float* logP  = ws + 16912;       // 8192
    // bf16 workspace (starts at float offset 25104, 16B aligned)
    unsigned short* ub   = (unsigned short*)(ws + 25104);
    unsigned short* Wt   = ub;                 // 4 x 65536 (q,k,v,o transposed bf16)
    unsigned short* pool = ub + 262144;        // 6M ushort
    unsigned short* q1b = pool;                // 1M
    unsigned short* k1b = pool + 1048576;      // 2M
    unsigned short* v1b = pool + 3145728;      // 2M
    unsigned short* c1b = pool + 5242880;      // 1M
    unsigned short* q2b = pool;                // 2M
    unsigned short* k2b = pool + 2097152;      // 1M
    unsigned short* v2b = pool + 3145728;      // 1M
    unsigned short* c2b = pool + 4194304;      // 2M

    (void)hipMemsetAsync(ws, 0, 528 * sizeof(float), stream);

    prep_wt_kernel<<<dim3(8, 8, 4), 256, 0, stream>>>(Wq, Wk, Wv, Wo, Wt);

    nig_gate_kernel<<<4096, 64, 0, stream>>>(H_D, maskD, nig_w, nig_b, gpreD, redD);
    nig_gate_kernel<<<8192, 64, 0, stream>>>(H_P, maskP, nig_w, nig_b, gpreP, redP);
    topk_kernel<<<dim3(8, 2), 256, 0, stream>>>(gpreD, maskD, outGD, logD, red4 + 0, red4 + 1, 512);
    topk_kernel<<<dim3(8, 4), 256, 0, stream>>>(gpreP, maskP, outGP, logP, red4 + 2, red4 + 3, 1024);

    // MHCA1: queries H_D (4096 rows), kv H_P (8192 rows)
    gemm_qkv_kernel<<<dim3(64, 2), 256, 0, stream>>>(H_D, Wt + 0 * 65536, bq, q1b);
    gemm_qkv_kernel<<<dim3(128, 2), 256, 0, stream>>>(H_P, Wt + 1 * 65536, bk, k1b);
    gemm_qkv_kernel<<<dim3(128, 2), 256, 0, stream>>>(H_P, Wt + 2 * 65536, bv, v1b);
    attn_mfma_kernel<1024><<<dim3(8, 64), 256, 0, stream>>>(q1b, k1b, v1b, logP, c1b, 512);
    gemm_o_ln_kernel<<<64, 256, 0, stream>>>(c1b, Wt + 3 * 65536, bo, H_D, ln_g, ln_b, outXd);

    // MHCA2: queries H_P (8192 rows), kv = Xd (4096 rows, f32 in d_out)
    gemm_qkv_kernel<<<dim3(128, 2), 256, 0, stream>>>(H_P, Wt + 0 * 65536, bq, q2b);
    gemm_qkv_kernel<<<dim3(64, 2), 256, 0, stream>>>(outXd, Wt + 1 * 65536, bk, k2b);
    gemm_qkv_kernel<<<dim3(64, 2), 256, 0, stream>>>(outXd, Wt + 2 * 65536, bv, v2b);
    attn_mfma_kernel<512><<<dim3(16, 64), 256, 0, stream>>>(q2b, k2b, v2b, logD, c2b, 1024);
    gemm_o_ln_kernel<<<128, 256, 0, stream>>>(c2b, Wt + 3 * 65536, bo, H_P, ln_g, ln_b, outXp);

    loss_kernel<<<1, 256, 0, stream>>>(redD, redP, red4, outLo);
}

// Round 7
// 242.519 us; speedup vs baseline: 9.5698x; 1.2203x over previous
//
#include <hip/hip_runtime.h>
#include <hip/hip_bf16.h>
#include <math.h>

typedef __attribute__((ext_vector_type(8))) short s8;
typedef __attribute__((ext_vector_type(8))) unsigned short us8;
typedef __attribute__((ext_vector_type(4))) float f4;

__device__ __forceinline__ unsigned short f2bf(float f) {
    unsigned int u = __float_as_uint(f);
    unsigned int r = u + 0x7FFFu + ((u >> 16) & 1u);   // RNE (no NaNs here)
    return (unsigned short)(r >> 16);
}

__device__ __forceinline__ float softplus_f(float x) {
    return (x > 0.f) ? x + log1pf(expf(-x)) : log1pf(expf(x));
}

// ============ fused: W->W^T bf16 prep  +  NIG gate (both tensors) ==========
__global__ __launch_bounds__(256) void prep_nig_kernel(
        const float* __restrict__ W0, const float* __restrict__ W1,
        const float* __restrict__ W2, const float* __restrict__ W3,
        unsigned short* __restrict__ Wt,
        const float* __restrict__ H_D, const int* __restrict__ maskD,
        const float* __restrict__ H_P, const int* __restrict__ maskP,
        const float* __restrict__ nw, const float* __restrict__ nb,
        float* __restrict__ gpreD, float* __restrict__ gpreP,
        float* __restrict__ redD, float* __restrict__ redP) {
    int bx = blockIdx.x;
    if (bx < 256) {                       // weight transpose tiles
        __shared__ float t[32][33];
        int wsel = bx >> 6, tile = bx & 63;
        const float* W = wsel == 0 ? W0 : wsel == 1 ? W1 : wsel == 2 ? W2 : W3;
        unsigned short* O = Wt + wsel * 65536;
        int k0 = (tile >> 3) * 32, n0 = (tile & 7) * 32;
        int r = threadIdx.x >> 5, c = threadIdx.x & 31;
#pragma unroll
        for (int i = 0; i < 4; ++i) t[r + i * 8][c] = W[(k0 + r + i * 8) * 256 + n0 + c];
        __syncthreads();
#pragma unroll
        for (int i = 0; i < 4; ++i) O[(n0 + r + i * 8) * 256 + k0 + c] = f2bf(t[c][r + i * 8]);
        return;
    }
    // NIG gate: 4 waves/block, one row each (f32 math — keep topk order exact)
    int row = (bx - 256) * 4 + (threadIdx.x >> 6);
    int lane = threadIdx.x & 63;
    const float* H; const int* mask; float* gpre; float* slots; int lr;
    if (row < 4096) { H = H_D; mask = maskD; gpre = gpreD; slots = redD; lr = row; }
    else            { H = H_P; mask = maskP; gpre = gpreP; slots = redP; lr = row - 4096; }
    const float* hp = H + (size_t)lr * 256;
    float a1 = 0.f, a2 = 0.f, a3 = 0.f;
    for (int d = lane; d < 256; d += 64) {
        float h = hp[d];
        a1 += h * nw[d * 4 + 1];
        a2 += h * nw[d * 4 + 2];
        a3 += h * nw[d * 4 + 3];
    }
#pragma unroll
    for (int o = 32; o; o >>= 1) {
        a1 += __shfl_xor(a1, o);
        a2 += __shfl_xor(a2, o);
        a3 += __shfl_xor(a3, o);
    }
    if (lane == 0) {
        float nu = softplus_f(a1 + nb[1]);
        float sa = softplus_f(a2 + nb[2]);          // alpha - 1
        float beta = softplus_f(a3 + nb[3]);
        float s2 = beta / (nu * sa + 1e-6f);
        float g = expf(-4.f * s2);
        g = fminf(fmaxf(g, 1e-4f), 1.f);
        gpre[lr] = (mask[lr] != 0) ? g : 0.f;
        atomicAdd(&slots[lr & 255], (1.f + sa) + beta);
    }
}

// ============ per-batch top-k, both tensors in one launch ==================
__device__ __forceinline__ void topk_body(
        const float* __restrict__ gpre, const int* __restrict__ mask,
        float* __restrict__ gout, float* __restrict__ logg,
        float* __restrict__ sg, float* __restrict__ sm,
        int N, int b, int by, float* grow, float* red) {
    int tid = threadIdx.x;
    int j = by * 256 + tid;
    for (int i = tid; i < N; i += 256) grow[i] = gpre[b * N + i];
    float cpart = 0.f;
    for (int i = tid; i < N; i += 256) cpart += (mask[b * N + i] != 0) ? 1.f : 0.f;
    red[tid] = cpart;
    __syncthreads();
    for (int s = 128; s; s >>= 1) { if (tid < s) red[tid] += red[tid + s]; __syncthreads(); }
    float count = red[0];
    __syncthreads();
    int k = (int)fmaxf(count * 0.5f, 1.0f);
    float gj = grow[j];
    int rank = 0;
    for (int i = 0; i < N; ++i) {
        float gi = grow[i];
        rank += (gi > gj || (gi == gj && i < j)) ? 1 : 0;
    }
    float gf = (rank < k) ? gj : 0.f;
    gout[b * N + j] = gf;
    logg[b * N + j] = logf(gf + 1e-8f);
    red[tid] = gf;
    __syncthreads();
    for (int s = 128; s; s >>= 1) { if (tid < s) red[tid] += red[tid + s]; __syncthreads(); }
    if (tid == 0) atomicAdd(sg, red[0]);
    __syncthreads();
    red[tid] = (mask[b * N + j] != 0) ? 1.f : 0.f;
    __syncthreads();
    for (int s = 128; s; s >>= 1) { if (tid < s) red[tid] += red[tid + s]; __syncthreads(); }
    if (tid == 0) atomicAdd(sm, red[0]);
}

__global__ void topk_both_kernel(
        const float* __restrict__ gpreD, const int* __restrict__ maskD,
        float* __restrict__ goutD, float* __restrict__ loggD,
        const float* __restrict__ gpreP, const int* __restrict__ maskP,
        float* __restrict__ goutP, float* __restrict__ loggP,
        float* __restrict__ red4) {
    __shared__ float grow[1024];
    __shared__ float red[256];
    int b = blockIdx.x, by = blockIdx.y;
    if (by < 2) topk_body(gpreD, maskD, goutD, loggD, red4 + 0, red4 + 1, 512, b, by, grow, red);
    else        topk_body(gpreP, maskP, goutP, loggP, red4 + 2, red4 + 3, 1024, b, by - 2, grow, red);
}

// ============ phase-1 projections (q1,k1,v1,q2) in one launch ==============
// block 256 = 4 waves; wave: 16 rows x 128 cols. A f32 -> bf16 in-reg.
__global__ __launch_bounds__(256) void qkv_mega_kernel(
        const float* __restrict__ H_D, const float* __restrict__ H_P,
        const unsigned short* __restrict__ Wt,
        const float* __restrict__ bq, const float* __restrict__ bk, const float* __restrict__ bv,
        unsigned short* __restrict__ q1b, unsigned short* __restrict__ k1b,
        unsigned short* __restrict__ v1b, unsigned short* __restrict__ q2b) {
    int bx = blockIdx.x;
    const float* A; const unsigned short* Wp; const float* bias; unsigned short* Cb; int idx;
    if (bx < 128)      { A = H_D; Wp = Wt;          bias = bq; Cb = q1b; idx = bx; }
    else if (bx < 384) { A = H_P; Wp = Wt + 65536;  bias = bk; Cb = k1b; idx = bx - 128; }
    else if (bx < 640) { A = H_P; Wp = Wt + 131072; bias = bv; Cb = v1b; idx = bx - 384; }
    else               { A = H_P; Wp = Wt;          bias = bq; Cb = q2b; idx = bx - 640; }
    const int tid = threadIdx.x, wid = tid >> 6, lane = tid & 63;
    const int g = lane >> 4, lo = lane & 15;
    const size_t row0 = (size_t)(idx >> 1) * 64 + wid * 16;
    const int n0 = (idx & 1) * 128;
    f4 acc[8];
#pragma unroll
    for (int f = 0; f < 8; ++f) acc[f] = (f4){0.f, 0.f, 0.f, 0.f};
    for (int k0 = 0; k0 < 256; k0 += 32) {
        s8 av;
        const float* ap = A + (row0 + lo) * 256 + k0 + g * 8;
        float4 x = *(const float4*)ap, y = *(const float4*)(ap + 4);
        av[0] = (short)f2bf(x.x); av[1] = (short)f2bf(x.y);
        av[2] = (short)f2bf(x.z); av[3] = (short)f2bf(x.w);
        av[4] = (short)f2bf(y.x); av[5] = (short)f2bf(y.y);
        av[6] = (short)f2bf(y.z); av[7] = (short)f2bf(y.w);
#pragma unroll
        for (int f = 0; f < 8; ++f) {
            s8 bfr = *(const s8*)&Wp[(size_t)(n0 + f * 16 + lo) * 256 + k0 + g * 8];
            acc[f] = __builtin_amdgcn_mfma_f32_16x16x32_bf16(av, bfr, acc[f], 0, 0, 0);
        }
    }
#pragma unroll
    for (int f = 0; f < 8; ++f) {
        int col = n0 + f * 16 + lo;
        float bv2 = bias[col];
#pragma unroll
        for (int r = 0; r < 4; ++r)
            Cb[(row0 + g * 4 + r) * 256 + col] = f2bf(acc[f][r] + bv2);
    }
}

// ============ k2,v2 projections from bf16 Xd in one launch =================
__global__ __launch_bounds__(256) void kv2_mega_kernel(
        const unsigned short* __restrict__ xdb, const unsigned short* __restrict__ Wt,
        const float* __restrict__ bk, const float* __restrict__ bv,
        unsigned short* __restrict__ k2b, unsigned short* __restrict__ v2b) {
    int bx = blockIdx.x;
    const unsigned short* Wp; const float* bias; unsigned short* Cb; int idx;
    if (bx < 128) { Wp = Wt + 65536;  bias = bk; Cb = k2b; idx = bx; }
    else          { Wp = Wt + 131072; bias = bv; Cb = v2b; idx = bx - 128; }
    const int tid = threadIdx.x, wid = tid >> 6, lane = tid & 63;
    const int g = lane >> 4, lo = lane & 15;
    const size_t row0 = (size_t)(idx >> 1) * 64 + wid * 16;
    const int n0 = (idx & 1) * 128;
    f4 acc[8];
#pragma unroll
    for (int f = 0; f < 8; ++f) acc[f] = (f4){0.f, 0.f, 0.f, 0.f};
    for (int k0 = 0; k0 < 256; k0 += 32) {
        s8 av = *(const s8*)&xdb[(row0 + lo) * 256 + k0 + g * 8];
#pragma unroll
        for (int f = 0; f < 8; ++f) {
            s8 bfr = *(const s8*)&Wp[(size_t)(n0 + f * 16 + lo) * 256 + k0 + g * 8];
            acc[f] = __builtin_amdgcn_mfma_f32_16x16x32_bf16(av, bfr, acc[f], 0, 0, 0);
        }
    }
#pragma unroll
    for (int f = 0; f < 8; ++f) {
        int col = n0 + f * 16 + lo;
        float bv2 = bias[col];
#pragma unroll
        for (int r = 0; r < 4; ++r)
            Cb[(row0 + g * 4 + r) * 256 + col] = f2bf(acc[f][r] + bv2);
    }
}

// ============ Wo GEMM + bias + residual + LayerNorm (+bf16 copy, +loss) ====
__global__ __launch_bounds__(256) void gemm_o_ln_kernel(
        const unsigned short* __restrict__ A, const unsigned short* __restrict__ Wt,
        const float* __restrict__ bias, const float* __restrict__ resid,
        const float* __restrict__ gam, const float* __restrict__ bet,
        float* __restrict__ Out, unsigned short* __restrict__ OutB,
        const float* __restrict__ redD, const float* __restrict__ redP,
        const float* __restrict__ red4, float* __restrict__ lossOut) {
    __shared__ float l1[256], l2[256];
    const int tid = threadIdx.x, wid = tid >> 6, lane = tid & 63;
    const int g = lane >> 4, lo = lane & 15;
    const size_t row0 = (size_t)blockIdx.x * 64 + wid * 16;
    f4 acc[16];
#pragma unroll
    for (int f = 0; f < 16; ++f) acc[f] = (f4){0.f, 0.f, 0.f, 0.f};
    for (int k0 = 0; k0 < 256; k0 += 32) {
        s8 af = *(const s8*)&A[(row0 + lo) * 256 + k0 + g * 8];
#pragma unroll
        for (int f = 0; f < 16; ++f) {
            s8 bfr = *(const s8*)&Wt[(size_t)(f * 16 + lo) * 256 + k0 + g * 8];
            acc[f] = __builtin_amdgcn_mfma_f32_16x16x32_bf16(af, bfr, acc[f], 0, 0, 0);
        }
    }
#pragma unroll
    for (int r = 0; r < 4; ++r) {
        size_t row = row0 + g * 4 + r;
        float s = 0.f;
#pragma unroll
        for (int f = 0; f < 16; ++f) {
            int col = f * 16 + lo;
            float v = acc[f][r] + bias[col] + resid[row * 256 + col];
            acc[f][r] = v;
            s += v;
        }
#pragma unroll
        for (int o = 1; o < 16; o <<= 1) s += __shfl_xor(s, o);
        float mean = s * (1.f / 256.f);
        float vs = 0.f;
#pragma unroll
        for (int f = 0; f < 16; ++f) {
            float dx = acc[f][r] - mean;
            vs += dx * dx;
        }
#pragma unroll
        for (int o = 1; o < 16; o <<= 1) vs += __shfl_xor(vs, o);
        float inv = rsqrtf(vs * (1.f / 256.f) + 1e-5f);
#pragma unroll
        for (int f = 0; f < 16; ++f) {
            int col = f * 16 + lo;
            float y = (acc[f][r] - mean) * inv * gam[col] + bet[col];
            Out[row * 256 + col] = y;
            if (OutB) OutB[row * 256 + col] = f2bf(y);
        }
    }
    // fold the scalar loss into block 0 (inputs were ready before this launch)
    if (lossOut && blockIdx.x == 0) {
        __syncthreads();
        l1[tid] = redD[tid];
        l2[tid] = redP[tid];
        __syncthreads();
        for (int s = 128; s; s >>= 1) {
            if (tid < s) { l1[tid] += l1[tid + s]; l2[tid] += l2[tid + s]; }
            __syncthreads();
        }
        if (tid == 0) {
            float t1 = red4[0] / (red4[1] + 1e-8f) - 0.3f;
            float t2 = red4[2] / (red4[3] + 1e-8f) - 0.3f;
            lossOut[0] = 0.01f * (t1 * t1) + 0.01f * (t2 * t2)
                       + 1e-3f * (l1[0] / 4096.f) + 1e-3f * (l2[0] / 8192.f);
        }
    }
}

// ============ fused flash attention (bf16 in, bf16 out) ====================
template <int NK>
__global__ __launch_bounds__(256) void attn_mfma_kernel(
        const unsigned short* __restrict__ qb, const unsigned short* __restrict__ kb,
        const unsigned short* __restrict__ vb, const float* __restrict__ logg,
        unsigned short* __restrict__ ctxb, int Nq) {
    __shared__ unsigned short Kf[2048];       // K-frags: [ksub(4)][lane(64)][8]
    __shared__ unsigned short Vf[2048];       // V-frags: [kh*2+dh][lane(64)][8]
    __shared__ unsigned short Pf[4][1152];    // per-wave P: [16 q][72 pitch]
    __shared__ float lg[64];

    const int tid = threadIdx.x;
    const int wid = tid >> 6, lane = tid & 63;
    const int g = lane >> 4, lo = lane & 15;
    const int b = blockIdx.y >> 3, h = blockIdx.y & 7;
    const int q0 = blockIdx.x * 64 + wid * 16;
    const size_t bq = (size_t)b * Nq, bk = (size_t)b * NK;
    const float scale = 0.17677669529663687f;  // 1/sqrt(32)

    s8 qf = *(const s8*)&qb[(bq + q0 + lo) * 256 + h * 32 + g * 8];

    f4 o0 = {0.f, 0.f, 0.f, 0.f}, o1 = {0.f, 0.f, 0.f, 0.f};
    float mrow[4] = {-3e38f, -3e38f, -3e38f, -3e38f};
    float lsum[4] = {0.f, 0.f, 0.f, 0.f};

    for (int kt = 0; kt < NK / 64; ++kt) {
        __syncthreads();   // prior tile fully consumed
        {
            int kloc = tid >> 2, quad = tid & 3;
            us8 kv8 = *(const us8*)&kb[(bk + kt * 64 + kloc) * 256 + h * 32 + quad * 8];
            *(us8*)&Kf[((kloc >> 4) << 9) + (quad * 16 + (kloc & 15)) * 8] = kv8;
            us8 vv8 = *(const us8*)&vb[(bk + kt * 64 + kloc) * 256 + h * 32 + quad * 8];
            int kh = kloc >> 5, gg = (kloc >> 3) & 3, j = kloc & 7;
            int dh = quad >> 1, l0 = (quad & 1) * 8;
            int vb0 = ((kh * 2 + dh) << 9) + gg * 128 + j;
#pragma unroll
            for (int jj = 0; jj < 8; ++jj) Vf[vb0 + (l0 + jj) * 8] = vv8[jj];
        }
        if (tid < 64) lg[tid] = logg[bk + kt * 64 + tid];
        __syncthreads();

        // ---- scores ----
        f4 sc[4];
#pragma unroll
        for (int ks = 0; ks < 4; ++ks) {
            s8 kfr = *(const s8*)&Kf[(ks << 9) + lane * 8];
            f4 z = {0.f, 0.f, 0.f, 0.f};
            f4 s4 = __builtin_amdgcn_mfma_f32_16x16x32_bf16(qf, kfr, z, 0, 0, 0);
            float lga = lg[ks * 16 + lo];
#pragma unroll
            for (int r = 0; r < 4; ++r) sc[ks][r] = s4[r] * scale + lga;
        }
        // ---- online softmax ----
        float vm[4];
#pragma unroll
        for (int r = 0; r < 4; ++r)
            vm[r] = fmaxf(fmaxf(sc[0][r], sc[1][r]), fmaxf(sc[2][r], sc[3][r]));
#pragma unroll
        for (int off = 1; off < 16; off <<= 1)
#pragma unroll
            for (int r = 0; r < 4; ++r) vm[r] = fmaxf(vm[r], __shfl_xor(vm[r], off));
        float al[4], ps[4];
#pragma unroll
        for (int r = 0; r < 4; ++r) {
            float mn = fmaxf(mrow[r], vm[r]);
            al[r] = __expf(mrow[r] - mn);
            mrow[r] = mn;
            ps[r] = 0.f;
        }
#pragma unroll
        for (int ks = 0; ks < 4; ++ks)
#pragma unroll
            for (int r = 0; r < 4; ++r) {
                float p = __expf(sc[ks][r] - mrow[r]);
                ps[r] += p;
                Pf[wid][(g * 4 + r) * 72 + ks * 16 + lo] = f2bf(p);
            }
#pragma unroll
        for (int off = 1; off < 16; off <<= 1)
#pragma unroll
            for (int r = 0; r < 4; ++r) ps[r] += __shfl_xor(ps[r], off);
#pragma unroll
        for (int r = 0; r < 4; ++r) {
            lsum[r] = lsum[r] * al[r] + ps[r];
            o0[r] *= al[r];
            o1[r] *= al[r];
        }
        // ---- PV ----
#pragma unroll
        for (int kh = 0; kh < 2; ++kh) {
            s8 pfr = *(const s8*)&Pf[wid][lo * 72 + kh * 32 + g * 8];
            s8 vf0 = *(const s8*)&Vf[((kh * 2 + 0) << 9) + lane * 8];
            o0 = __builtin_amdgcn_mfma_f32_16x16x32_bf16(pfr, vf0, o0, 0, 0, 0);
            s8 vf1 = *(const s8*)&Vf[((kh * 2 + 1) << 9) + lane * 8];
            o1 = __builtin_amdgcn_mfma_f32_16x16x32_bf16(pfr, vf1, o1, 0, 0, 0);
        }
    }
    // ---- epilogue (bf16 ctx) ----
#pragma unroll
    for (int r = 0; r < 4; ++r) {
        float inv = 1.f / lsum[r];
        unsigned short* cp = ctxb + (bq + q0 + g * 4 + r) * 256 + h * 32;
        cp[lo] = f2bf(o0[r] * inv);
        cp[16 + lo] = f2bf(o1[r] * inv);
    }
}

extern "C" void kernel_launch(void* const* d_in, const int* in_sizes, int n_in,
                              void* d_out, int out_size, void* d_ws, size_t ws_size,
                              hipStream_t stream) {
    (void)in_sizes; (void)n_in; (void)out_size; (void)ws_size;
    const float* H_D   = (const float*)d_in[0];
    const int*   maskD = (const int*)d_in[1];
    const float* H_P   = (const float*)d_in[2];
    const int*   maskP = (const int*)d_in[3];
    const float* nig_w = (const float*)d_in[4];
    const float* nig_b = (const float*)d_in[5];
    const float* Wq = (const float*)d_in[6];
    const float* bq = (const float*)d_in[7];
    const float* Wk = (const float*)d_in[8];
    const float* bk = (const float*)d_in[9];
    const float* Wv = (const float*)d_in[10];
    const float* bv = (const float*)d_in[11];
    const float* Wo = (const float*)d_in[12];
    const float* bo = (const float*)d_in[13];
    const float* ln_g = (const float*)d_in[14];
    const float* ln_b = (const float*)d_in[15];
    float* out = (float*)d_out;
    float* ws = (float*)d_ws;

    // output offsets (f32): Xd, Xp, g_D, g_P, loss
    float* outXd = out + 0;
    float* outXp = out + 1048576;
    float* outGD = out + 3145728;
    float* outGP = out + 3149824;
    float* outLo = out + 3158016;

    // f32 workspace
    float* redD  = ws;               // 256 slots
    float* redP  = ws + 256;         // 256 slots
    float* red4  = ws + 512;         // 16 (4 used: sgD,smD,sgP,smP)
    float* gpreD = ws + 528;         // 4096
    float* gpreP = ws + 4624;        // 8192
    float* logD  = ws + 12816;       // 4096
    float* logP  = ws + 16912;       // 8192
    // bf16 workspace (starts at float offset 25104, 16B aligned)
    unsigned short* ub   = (unsigned short*)(ws + 25104);
    unsigned short* Wt   = ub;                   // 4 x 65536 (q,k,v,o transposed bf16)
    unsigned short* pool = ub + 262144;
    unsigned short* q1b = pool;                  // 1M
    unsigned short* k1b = pool + 1048576;        // 2M
    unsigned short* v1b = pool + 3145728;        // 2M
    unsigned short* q2b = pool + 5242880;        // 2M (live through phase 1!)
    unsigned short* c1b = pool + 7340032;        // 1M
    unsigned short* xdb = pool + 8388608;        // 1M
    unsigned short* k2b = pool + 9437184;        // 1M
    unsigned short* v2b = pool + 10485760;       // 1M
    unsigned short* c2b = pool + 11534336;       // 2M

    (void)hipMemsetAsync(ws, 0, 528 * sizeof(float), stream);

    // 1) weight prep + NIG gates (one launch)
    prep_nig_kernel<<<3328, 256, 0, stream>>>(Wq, Wk, Wv, Wo, Wt,
                                              H_D, maskD, H_P, maskP,
                                              nig_w, nig_b, gpreD, gpreP, redD, redP);
    // 2) q1,k1,v1,q2 projections (one launch)
    qkv_mega_kernel<<<896, 256, 0, stream>>>(H_D, H_P, Wt, bq, bk, bv, q1b, k1b, v1b, q2b);
    // 3) top-k for both tensors (one launch)
    topk_both_kernel<<<dim3(8, 6), 256, 0, stream>>>(gpreD, maskD, outGD, logD,
                                                     gpreP, maskP, outGP, logP, red4);
    // 4) MHCA1 attention
    attn_mfma_kernel<1024><<<dim3(8, 64), 256, 0, stream>>>(q1b, k1b, v1b, logP, c1b, 512);
    // 5) Wo+LN (writes f32 Xd to d_out and bf16 copy for k2/v2)
    gemm_o_ln_kernel<<<64, 256, 0, stream>>>(c1b, Wt + 3 * 65536, bo, H_D, ln_g, ln_b,
                                             outXd, xdb, nullptr, nullptr, nullptr, nullptr);
    // 6) k2,v2 projections (one launch, bf16 A)
    kv2_mega_kernel<<<256, 256, 0, stream>>>(xdb, Wt, bk, bv, k2b, v2b);
    // 7) MHCA2 attention
    attn_mfma_kernel<512><<<dim3(16, 64), 256, 0, stream>>>(q2b, k2b, v2b, logD, c2b, 1024);
    // 8) Wo+LN (+ folded scalar loss)
    gemm_o_ln_kernel<<<128, 256, 0, stream>>>(c2b, Wt + 3 * 65536, bo, H_P, ln_g, ln_b,
                                              outXp, nullptr, redD, redP, red4, outLo);
}

// Round 8
// 173.259 us; speedup vs baseline: 13.3953x; 1.3997x over previous
//
#include <hip/hip_runtime.h>
#include <hip/hip_bf16.h>
#include <math.h>

typedef __attribute__((ext_vector_type(8))) short s8;
typedef __attribute__((ext_vector_type(8))) unsigned short us8;
typedef __attribute__((ext_vector_type(4))) float f4;

__device__ __forceinline__ unsigned short f2bf(float f) {
    unsigned int u = __float_as_uint(f);
    unsigned int r = u + 0x7FFFu + ((u >> 16) & 1u);   // RNE (no NaNs here)
    return (unsigned short)(r >> 16);
}

__device__ __forceinline__ float softplus_f(float x) {
    return (x > 0.f) ? x + log1pf(expf(-x)) : log1pf(expf(x));
}

// ============ fused: W->W^T bf16 prep  +  NIG gate (both tensors) ==========
__global__ __launch_bounds__(256) void prep_nig_kernel(
        const float* __restrict__ W0, const float* __restrict__ W1,
        const float* __restrict__ W2, const float* __restrict__ W3,
        unsigned short* __restrict__ Wt,
        const float* __restrict__ H_D, const int* __restrict__ maskD,
        const float* __restrict__ H_P, const int* __restrict__ maskP,
        const float* __restrict__ nw, const float* __restrict__ nb,
        float* __restrict__ gpreD, float* __restrict__ gpreP,
        float* __restrict__ abD, float* __restrict__ abP) {
    int bx = blockIdx.x;
    if (bx < 256) {                       // weight transpose tiles
        __shared__ float t[32][33];
        int wsel = bx >> 6, tile = bx & 63;
        const float* W = wsel == 0 ? W0 : wsel == 1 ? W1 : wsel == 2 ? W2 : W3;
        unsigned short* O = Wt + wsel * 65536;
        int k0 = (tile >> 3) * 32, n0 = (tile & 7) * 32;
        int r = threadIdx.x >> 5, c = threadIdx.x & 31;
#pragma unroll
        for (int i = 0; i < 4; ++i) t[r + i * 8][c] = W[(k0 + r + i * 8) * 256 + n0 + c];
        __syncthreads();
#pragma unroll
        for (int i = 0; i < 4; ++i) O[(n0 + r + i * 8) * 256 + k0 + c] = f2bf(t[c][r + i * 8]);
        return;
    }
    // NIG gate: 4 waves/block, one row each (f32 math — keep topk order exact)
    int row = (bx - 256) * 4 + (threadIdx.x >> 6);
    int lane = threadIdx.x & 63;
    const float* H; const int* mask; float* gpre; float* ab; int lr;
    if (row < 4096) { H = H_D; mask = maskD; gpre = gpreD; ab = abD; lr = row; }
    else            { H = H_P; mask = maskP; gpre = gpreP; ab = abP; lr = row - 4096; }
    const float* hp = H + (size_t)lr * 256;
    float a1 = 0.f, a2 = 0.f, a3 = 0.f;
    for (int d = lane; d < 256; d += 64) {
        float h = hp[d];
        a1 += h * nw[d * 4 + 1];
        a2 += h * nw[d * 4 + 2];
        a3 += h * nw[d * 4 + 3];
    }
#pragma unroll
    for (int o = 32; o; o >>= 1) {
        a1 += __shfl_xor(a1, o);
        a2 += __shfl_xor(a2, o);
        a3 += __shfl_xor(a3, o);
    }
    if (lane == 0) {
        float nu = softplus_f(a1 + nb[1]);
        float sa = softplus_f(a2 + nb[2]);          // alpha - 1
        float beta = softplus_f(a3 + nb[3]);
        float s2 = beta / (nu * sa + 1e-6f);
        float g = expf(-4.f * s2);
        g = fminf(fmaxf(g, 1e-4f), 1.f);
        gpre[lr] = (mask[lr] != 0) ? g : 0.f;
        ab[lr] = (1.f + sa) + beta;                 // alpha + beta (no atomic)
    }
}

// ============ per-batch top-k body (partial sums to dedicated slots) =======
__device__ __forceinline__ void topk_body(
        const float* __restrict__ gpre, const int* __restrict__ mask,
        float* __restrict__ gout, float* __restrict__ logg,
        float* __restrict__ sgArr, float* __restrict__ smArr,
        int N, int b, int by, int bslot, float* grow, float* red) {
    int tid = threadIdx.x;
    int j = by * 256 + tid;
    for (int i = tid; i < N; i += 256) grow[i] = gpre[b * N + i];
    float cpart = 0.f;
    for (int i = tid; i < N; i += 256) cpart += (mask[b * N + i] != 0) ? 1.f : 0.f;
    red[tid] = cpart;
    __syncthreads();
    for (int s = 128; s; s >>= 1) { if (tid < s) red[tid] += red[tid + s]; __syncthreads(); }
    float count = red[0];
    __syncthreads();
    int k = (int)fmaxf(count * 0.5f, 1.0f);
    float gj = grow[j];
    int rank = 0;
    for (int i = 0; i < N; ++i) {
        float gi = grow[i];
        rank += (gi > gj || (gi == gj && i < j)) ? 1 : 0;
    }
    float gf = (rank < k) ? gj : 0.f;
    gout[b * N + j] = gf;
    logg[b * N + j] = logf(gf + 1e-8f);
    red[tid] = gf;
    __syncthreads();
    for (int s = 128; s; s >>= 1) { if (tid < s) red[tid] += red[tid + s]; __syncthreads(); }
    if (tid == 0) sgArr[bslot] = red[0];
    __syncthreads();
    red[tid] = (mask[b * N + j] != 0) ? 1.f : 0.f;
    __syncthreads();
    for (int s = 128; s; s >>= 1) { if (tid < s) red[tid] += red[tid + s]; __syncthreads(); }
    if (tid == 0) smArr[bslot] = red[0];
}

// ============ mega launch: q1,k1,v1,q2 projections + topk + EDL reduce =====
__global__ __launch_bounds__(256) void qkv_topk_kernel(
        const float* __restrict__ H_D, const float* __restrict__ H_P,
        const unsigned short* __restrict__ Wt,
        const float* __restrict__ bq, const float* __restrict__ bk, const float* __restrict__ bv,
        unsigned short* __restrict__ q1b, unsigned short* __restrict__ k1b,
        unsigned short* __restrict__ v1b, unsigned short* __restrict__ q2b,
        const float* __restrict__ gpreD, const int* __restrict__ maskD,
        float* __restrict__ goutD, float* __restrict__ loggD,
        const float* __restrict__ gpreP, const int* __restrict__ maskP,
        float* __restrict__ goutP, float* __restrict__ loggP,
        float* __restrict__ sgD, float* __restrict__ smD,
        float* __restrict__ sgP, float* __restrict__ smP,
        const float* __restrict__ abD, const float* __restrict__ abP,
        float* __restrict__ edl2) {
    __shared__ float grow[1024];
    __shared__ float red[256];
    int bx = blockIdx.x;
    int tid = threadIdx.x;
    if (bx == 944) {                      // EDL sums
        float s1 = 0.f, s2 = 0.f;
        for (int i = tid; i < 4096; i += 256) s1 += abD[i];
        for (int i = tid; i < 8192; i += 256) s2 += abP[i];
        red[tid] = s1;
        __syncthreads();
        for (int s = 128; s; s >>= 1) { if (tid < s) red[tid] += red[tid + s]; __syncthreads(); }
        if (tid == 0) edl2[0] = red[0];
        __syncthreads();
        red[tid] = s2;
        __syncthreads();
        for (int s = 128; s; s >>= 1) { if (tid < s) red[tid] += red[tid + s]; __syncthreads(); }
        if (tid == 0) edl2[1] = red[0];
        return;
    }
    if (bx >= 896) {                      // top-k
        int tb = bx - 896;
        int b = tb & 7, by = tb >> 3;
        if (by < 2) topk_body(gpreD, maskD, goutD, loggD, sgD, smD, 512, b, by, b * 2 + by, grow, red);
        else        topk_body(gpreP, maskP, goutP, loggP, sgP, smP, 1024, b, by - 2, b * 4 + (by - 2), grow, red);
        return;
    }
    // QKV projections
    const float* A; const unsigned short* Wp; const float* bias; unsigned short* Cb; int idx;
    if (bx < 128)      { A = H_D; Wp = Wt;          bias = bq; Cb = q1b; idx = bx; }
    else if (bx < 384) { A = H_P; Wp = Wt + 65536;  bias = bk; Cb = k1b; idx = bx - 128; }
    else if (bx < 640) { A = H_P; Wp = Wt + 131072; bias = bv; Cb = v1b; idx = bx - 384; }
    else               { A = H_P; Wp = Wt;          bias = bq; Cb = q2b; idx = bx - 640; }
    const int wid = tid >> 6, lane = tid & 63;
    const int g = lane >> 4, lo = lane & 15;
    const size_t row0 = (size_t)(idx >> 1) * 64 + wid * 16;
    const int n0 = (idx & 1) * 128;
    f4 acc[8];
#pragma unroll
    for (int f = 0; f < 8; ++f) acc[f] = (f4){0.f, 0.f, 0.f, 0.f};
    for (int k0 = 0; k0 < 256; k0 += 32) {
        s8 av;
        const float* ap = A + (row0 + lo) * 256 + k0 + g * 8;
        float4 x = *(const float4*)ap, y = *(const float4*)(ap + 4);
        av[0] = (short)f2bf(x.x); av[1] = (short)f2bf(x.y);
        av[2] = (short)f2bf(x.z); av[3] = (short)f2bf(x.w);
        av[4] = (short)f2bf(y.x); av[5] = (short)f2bf(y.y);
        av[6] = (short)f2bf(y.z); av[7] = (short)f2bf(y.w);
#pragma unroll
        for (int f = 0; f < 8; ++f) {
            s8 bfr = *(const s8*)&Wp[(size_t)(n0 + f * 16 + lo) * 256 + k0 + g * 8];
            acc[f] = __builtin_amdgcn_mfma_f32_16x16x32_bf16(av, bfr, acc[f], 0, 0, 0);
        }
    }
#pragma unroll
    for (int f = 0; f < 8; ++f) {
        int col = n0 + f * 16 + lo;
        float bv2 = bias[col];
#pragma unroll
        for (int r = 0; r < 4; ++r)
            Cb[(row0 + g * 4 + r) * 256 + col] = f2bf(acc[f][r] + bv2);
    }
}

// ============ k2,v2 projections from bf16 Xd in one launch =================
__global__ __launch_bounds__(256) void kv2_mega_kernel(
        const unsigned short* __restrict__ xdb, const unsigned short* __restrict__ Wt,
        const float* __restrict__ bk, const float* __restrict__ bv,
        unsigned short* __restrict__ k2b, unsigned short* __restrict__ v2b) {
    int bx = blockIdx.x;
    const unsigned short* Wp; const float* bias; unsigned short* Cb; int idx;
    if (bx < 128) { Wp = Wt + 65536;  bias = bk; Cb = k2b; idx = bx; }
    else          { Wp = Wt + 131072; bias = bv; Cb = v2b; idx = bx - 128; }
    const int tid = threadIdx.x, wid = tid >> 6, lane = tid & 63;
    const int g = lane >> 4, lo = lane & 15;
    const size_t row0 = (size_t)(idx >> 1) * 64 + wid * 16;
    const int n0 = (idx & 1) * 128;
    f4 acc[8];
#pragma unroll
    for (int f = 0; f < 8; ++f) acc[f] = (f4){0.f, 0.f, 0.f, 0.f};
    for (int k0 = 0; k0 < 256; k0 += 32) {
        s8 av = *(const s8*)&xdb[(row0 + lo) * 256 + k0 + g * 8];
#pragma unroll
        for (int f = 0; f < 8; ++f) {
            s8 bfr = *(const s8*)&Wp[(size_t)(n0 + f * 16 + lo) * 256 + k0 + g * 8];
            acc[f] = __builtin_amdgcn_mfma_f32_16x16x32_bf16(av, bfr, acc[f], 0, 0, 0);
        }
    }
#pragma unroll
    for (int f = 0; f < 8; ++f) {
        int col = n0 + f * 16 + lo;
        float bv2 = bias[col];
#pragma unroll
        for (int r = 0; r < 4; ++r)
            Cb[(row0 + g * 4 + r) * 256 + col] = f2bf(acc[f][r] + bv2);
    }
}

// ============ Wo GEMM + bias + residual + LayerNorm (1 wave, 16 rows) ======
__global__ __launch_bounds__(64) void gemm_o_ln_kernel(
        const unsigned short* __restrict__ A, const unsigned short* __restrict__ Wt,
        const float* __restrict__ bias, const float* __restrict__ resid,
        const float* __restrict__ gam, const float* __restrict__ bet,
        float* __restrict__ Out, unsigned short* __restrict__ OutB,
        const float* __restrict__ sgD, const float* __restrict__ smD,
        const float* __restrict__ sgP, const float* __restrict__ smP,
        const float* __restrict__ edl2, float* __restrict__ lossOut) {
    const int lane = threadIdx.x;
    const int g = lane >> 4, lo = lane & 15;
    const size_t row0 = (size_t)blockIdx.x * 16;
    f4 acc[16];
#pragma unroll
    for (int f = 0; f < 16; ++f) acc[f] = (f4){0.f, 0.f, 0.f, 0.f};
    for (int k0 = 0; k0 < 256; k0 += 32) {
        s8 af = *(const s8*)&A[(row0 + lo) * 256 + k0 + g * 8];
#pragma unroll
        for (int f = 0; f < 16; ++f) {
            s8 bfr = *(const s8*)&Wt[(size_t)(f * 16 + lo) * 256 + k0 + g * 8];
            acc[f] = __builtin_amdgcn_mfma_f32_16x16x32_bf16(af, bfr, acc[f], 0, 0, 0);
        }
    }
#pragma unroll
    for (int r = 0; r < 4; ++r) {
        size_t row = row0 + g * 4 + r;
        float s = 0.f;
#pragma unroll
        for (int f = 0; f < 16; ++f) {
            int col = f * 16 + lo;
            float v = acc[f][r] + bias[col] + resid[row * 256 + col];
            acc[f][r] = v;
            s += v;
        }
#pragma unroll
        for (int o = 1; o < 16; o <<= 1) s += __shfl_xor(s, o);
        float mean = s * (1.f / 256.f);
        float vs = 0.f;
#pragma unroll
        for (int f = 0; f < 16; ++f) {
            float dx = acc[f][r] - mean;
            vs += dx * dx;
        }
#pragma unroll
        for (int o = 1; o < 16; o <<= 1) vs += __shfl_xor(vs, o);
        float inv = rsqrtf(vs * (1.f / 256.f) + 1e-5f);
#pragma unroll
        for (int f = 0; f < 16; ++f) {
            int col = f * 16 + lo;
            float y = (acc[f][r] - mean) * inv * gam[col] + bet[col];
            Out[row * 256 + col] = y;
            if (OutB) OutB[row * 256 + col] = f2bf(y);
        }
    }
    // scalar loss fold (block 0 only; inputs ready dispatches earlier)
    if (lossOut && blockIdx.x == 0) {
        float sgd = 0.f, smd = 0.f, sgp = 0.f, smp = 0.f;
        if (lane < 16) { sgd = sgD[lane]; smd = smD[lane]; }
        if (lane < 32) { sgp = sgP[lane]; smp = smP[lane]; }
#pragma unroll
        for (int o = 16; o; o >>= 1) { sgp += __shfl_xor(sgp, o); smp += __shfl_xor(smp, o); }
#pragma unroll
        for (int o = 8; o; o >>= 1) { sgd += __shfl_xor(sgd, o); smd += __shfl_xor(smd, o); }
        if (lane == 0) {
            float t1 = sgd / (smd + 1e-8f) - 0.3f;
            float t2 = sgp / (smp + 1e-8f) - 0.3f;
            lossOut[0] = 0.01f * (t1 * t1) + 0.01f * (t2 * t2)
                       + 1e-3f * (edl2[0] / 4096.f) + 1e-3f * (edl2[1] / 8192.f);
        }
    }
}

// ============ fused flash attention: 1-barrier prefetch pipeline ===========
template <int NK>
__global__ __launch_bounds__(256) void attn_mfma_kernel(
        const unsigned short* __restrict__ qb, const unsigned short* __restrict__ kb,
        const unsigned short* __restrict__ vb, const float* __restrict__ logg,
        unsigned short* __restrict__ ctxb, int Nq) {
    __shared__ unsigned short Kf[2][2048];    // K-frags: [ksub(4)][lane(64)][8]
    __shared__ unsigned short Vf[2][2048];    // V-frags: [kh*2+dh][lane(64)][8]
    __shared__ unsigned short Pf[4][1152];    // per-wave P: [16 q][72 pitch]
    __shared__ float lg[2][64];
    constexpr int NT = NK / 64;

    const int tid = threadIdx.x;
    const int wid = tid >> 6, lane = tid & 63;
    const int g = lane >> 4, lo = lane & 15;
    const int b = blockIdx.y >> 3, h = blockIdx.y & 7;
    const int q0 = blockIdx.x * 64 + wid * 16;
    const size_t bq = (size_t)b * Nq, bk = (size_t)b * NK;
    const float scale = 0.17677669529663687f;  // 1/sqrt(32)

    // staging constants
    const int kloc = tid >> 2, quad = tid & 3;
    const size_t gbase = (bk + kloc) * 256 + h * 32 + quad * 8;
    const int kfa = ((kloc >> 4) << 9) + (quad * 16 + (kloc & 15)) * 8;
    const int vkh = kloc >> 5, vgg = (kloc >> 3) & 3, vj = kloc & 7;
    const int vdh = quad >> 1, vl0 = (quad & 1) * 8;
    const int vb0 = ((vkh * 2 + vdh) << 9) + vgg * 128 + vj;

    s8 qf = *(const s8*)&qb[(bq + q0 + lo) * 256 + h * 32 + g * 8];

    f4 o0 = {0.f, 0.f, 0.f, 0.f}, o1 = {0.f, 0.f, 0.f, 0.f};
    float mrow[4] = {-3e38f, -3e38f, -3e38f, -3e38f};
    float lsum[4] = {0.f, 0.f, 0.f, 0.f};

    // prologue: tile 0 -> regs -> LDS[0]
    us8 kreg = *(const us8*)&kb[gbase];
    us8 vreg = *(const us8*)&vb[gbase];
    float lgreg = (tid < 64) ? logg[bk + tid] : 0.f;
    *(us8*)&Kf[0][kfa] = kreg;
#pragma unroll
    for (int jj = 0; jj < 8; ++jj) Vf[0][vb0 + (vl0 + jj) * 8] = vreg[jj];
    if (tid < 64) lg[0][tid] = lgreg;

    for (int t = 0; t < NT; ++t) {
        const int cur = t & 1;
        if (t + 1 < NT) {                 // issue next tile's global loads early
            size_t ga = gbase + (size_t)(t + 1) * 64 * 256;
            kreg = *(const us8*)&kb[ga];
            vreg = *(const us8*)&vb[ga];
            if (tid < 64) lgreg = logg[bk + (t + 1) * 64 + tid];
        }
        __syncthreads();                  // LDS[cur] ready for all waves

        // ---- scores ----
        f4 sc[4];
#pragma unroll
        for (int ks = 0; ks < 4; ++ks) {
            s8 kfr = *(const s8*)&Kf[cur][(ks << 9) + lane * 8];
            f4 z = {0.f, 0.f, 0.f, 0.f};
            f4 s4 = __builtin_amdgcn_mfma_f32_16x16x32_bf16(qf, kfr, z, 0, 0, 0);
            float lga = lg[cur][ks * 16 + lo];
#pragma unroll
            for (int r = 0; r < 4; ++r) sc[ks][r] = s4[r] * scale + lga;
        }
        // ---- online softmax ----
        float vm[4];
#pragma unroll
        for (int r = 0; r < 4; ++r)
            vm[r] = fmaxf(fmaxf(sc[0][r], sc[1][r]), fmaxf(sc[2][r], sc[3][r]));
#pragma unroll
        for (int off = 1; off < 16; off <<= 1)
#pragma unroll
            for (int r = 0; r < 4; ++r) vm[r] = fmaxf(vm[r], __shfl_xor(vm[r], off));
        float al[4], ps[4];
#pragma unroll
        for (int r = 0; r < 4; ++r) {
            float mn = fmaxf(mrow[r], vm[r]);
            al[r] = __expf(mrow[r] - mn);
            mrow[r] = mn;
            ps[r] = 0.f;
        }
#pragma unroll
        for (int ks = 0; ks < 4; ++ks)
#pragma unroll
            for (int r = 0; r < 4; ++r) {
                float p = __expf(sc[ks][r] - mrow[r]);
                ps[r] += p;
                Pf[wid][(g * 4 + r) * 72 + ks * 16 + lo] = f2bf(p);
            }
#pragma unroll
        for (int off = 1; off < 16; off <<= 1)
#pragma unroll
            for (int r = 0; r < 4; ++r) ps[r] += __shfl_xor(ps[r], off);
#pragma unroll
        for (int r = 0; r < 4; ++r) {
            lsum[r] = lsum[r] * al[r] + ps[r];
            o0[r] *= al[r];
            o1[r] *= al[r];
        }
        // ---- PV ----
#pragma unroll
        for (int kh = 0; kh < 2; ++kh) {
            s8 pfr = *(const s8*)&Pf[wid][lo * 72 + kh * 32 + g * 8];
            s8 vf0 = *(const s8*)&Vf[cur][((kh * 2 + 0) << 9) + lane * 8];
            o0 = __builtin_amdgcn_mfma_f32_16x16x32_bf16(pfr, vf0, o0, 0, 0, 0);
            s8 vf1 = *(const s8*)&Vf[cur][((kh * 2 + 1) << 9) + lane * 8];
            o1 = __builtin_amdgcn_mfma_f32_16x16x32_bf16(pfr, vf1, o1, 0, 0, 0);
        }
        // ---- write next tile regs -> LDS[cur^1] (safe: all waves past barrier
        //      have finished compute(t-1), the last reader of buf cur^1) ----
        if (t + 1 < NT) {
            const int nxt = cur ^ 1;
            *(us8*)&Kf[nxt][kfa] = kreg;
#pragma unroll
            for (int jj = 0; jj < 8; ++jj) Vf[nxt][vb0 + (vl0 + jj) * 8] = vreg[jj];
            if (tid < 64) lg[nxt][tid] = lgreg;
        }
    }
    // ---- epilogue (bf16 ctx) ----
#pragma unroll
    for (int r = 0; r < 4; ++r) {
        float inv = 1.f / lsum[r];
        unsigned short* cp = ctxb + (bq + q0 + g * 4 + r) * 256 + h * 32;
        cp[lo] = f2bf(o0[r] * inv);
        cp[16 + lo] = f2bf(o1[r] * inv);
    }
}

extern "C" void kernel_launch(void* const* d_in, const int* in_sizes, int n_in,
                              void* d_out, int out_size, void* d_ws, size_t ws_size,
                              hipStream_t stream) {
    (void)in_sizes; (void)n_in; (void)out_size; (void)ws_size;
    const float* H_D   = (const float*)d_in[0];
    const int*   maskD = (const int*)d_in[1];
    const float* H_P   = (const float*)d_in[2];
    const int*   maskP = (const int*)d_in[3];
    const float* nig_w = (const float*)d_in[4];
    const float* nig_b = (const float*)d_in[5];
    const float* Wq = (const float*)d_in[6];
    const float* bq = (const float*)d_in[7];
    const float* Wk = (const float*)d_in[8];
    const float* bk = (const float*)d_in[9];
    const float* Wv = (const float*)d_in[10];
    const float* bv = (const float*)d_in[11];
    const float* Wo = (const float*)d_in[12];
    const float* bo = (const float*)d_in[13];
    const float* ln_g = (const float*)d_in[14];
    const float* ln_b = (const float*)d_in[15];
    float* out = (float*)d_out;
    float* ws = (float*)d_ws;

    // output offsets (f32): Xd, Xp, g_D, g_P, loss
    float* outXd = out + 0;
    float* outXp = out + 1048576;
    float* outGD = out + 3145728;
    float* outGP = out + 3149824;
    float* outLo = out + 3158016;

    // f32 workspace (all written deterministically every call — no memset)
    float* abD   = ws;               // 4096
    float* abP   = ws + 4096;        // 8192
    float* sgD   = ws + 12288;       // 16
    float* smD   = ws + 12304;       // 16
    float* sgP   = ws + 12320;       // 32
    float* smP   = ws + 12352;       // 32
    float* edl2  = ws + 12384;       // 2
    float* gpreD = ws + 12416;       // 4096
    float* gpreP = ws + 16512;       // 8192
    float* logD  = ws + 24704;       // 4096
    float* logP  = ws + 28800;       // 8192
    // bf16 workspace (starts at float offset 36992, 16B aligned)
    unsigned short* ub   = (unsigned short*)(ws + 36992);
    unsigned short* Wt   = ub;                   // 4 x 65536
    unsigned short* pool = ub + 262144;
    unsigned short* q1b = pool;                  // 1M
    unsigned short* k1b = pool + 1048576;        // 2M
    unsigned short* v1b = pool + 3145728;        // 2M
    unsigned short* q2b = pool + 5242880;        // 2M (live through phase 1)
    unsigned short* c1b = pool + 7340032;        // 1M
    unsigned short* xdb = pool + 8388608;        // 1M
    unsigned short* k2b = pool + 9437184;        // 1M
    unsigned short* v2b = pool + 10485760;       // 1M
    unsigned short* c2b = pool + 11534336;       // 2M

    // 1) weight prep + NIG gates
    prep_nig_kernel<<<3328, 256, 0, stream>>>(Wq, Wk, Wv, Wo, Wt,
                                              H_D, maskD, H_P, maskP,
                                              nig_w, nig_b, gpreD, gpreP, abD, abP);
    // 2) q1,k1,v1,q2 projections + top-k + EDL reduce (one launch)
    qkv_topk_kernel<<<945, 256, 0, stream>>>(H_D, H_P, Wt, bq, bk, bv,
                                             q1b, k1b, v1b, q2b,
                                             gpreD, maskD, outGD, logD,
                                             gpreP, maskP, outGP, logP,
                                             sgD, smD, sgP, smP, abD, abP, edl2);
    // 3) MHCA1 attention
    attn_mfma_kernel<1024><<<dim3(8, 64), 256, 0, stream>>>(q1b, k1b, v1b, logP, c1b, 512);
    // 4) Wo+LN (f32 Xd to d_out + bf16 copy)
    gemm_o_ln_kernel<<<256, 64, 0, stream>>>(c1b, Wt + 3 * 65536, bo, H_D, ln_g, ln_b,
                                             outXd, xdb, nullptr, nullptr, nullptr, nullptr,
                                             nullptr, nullptr);
    // 5) k2,v2 projections
    kv2_mega_kernel<<<256, 256, 0, stream>>>(xdb, Wt, bk, bv, k2b, v2b);
    // 6) MHCA2 attention
    attn_mfma_kernel<512><<<dim3(16, 64), 256, 0, stream>>>(q2b, k2b, v2b, logD, c2b, 1024);
    // 7) Wo+LN + scalar loss
    gemm_o_ln_kernel<<<512, 64, 0, stream>>>(c2b, Wt + 3 * 65536, bo, H_P, ln_g, ln_b,
                                             outXp, nullptr, sgD, smD, sgP, smP, edl2, outLo);
}